// Round 7
// baseline (2043.792 us; speedup 1.0000x reference)
//
#include <hip/hip_runtime.h>
#include <hip/hip_fp16.h>

#define V_ 50000
#define E_ 512
#define H_ 1024
#define B_ 128
#define T_ 512
#define NG 4096  // 4*H

typedef _Float16 half8 __attribute__((ext_vector_type(8)));
typedef float f32x4 __attribute__((ext_vector_type(4)));

// ---- workspace layout (bytes) ----
static constexpr size_t WX_OFF   = 0;                                        // 4 MiB: Wx f16 B-frags [ntg 256][kt 16][L 64] half8
static constexpr size_t WH_OFF   = (size_t)4 << 20;                          // 8 MiB: Wh f16 B-frags [hblk 32][nt 8][kt 32][L 64] half8
static constexpr size_t BG_OFF   = (size_t)12 << 20;                         // 16 KiB: bias concat f32 [4096]
static constexpr size_t HBUF_OFF = ((size_t)12 << 20) + ((size_t)64 << 10);  // 512 KiB: h dbuf [2][g 8][kk 32][L 64] half8 (A-frag layout)
static constexpr size_t BAR_OFF  = ((size_t)12 << 20) + ((size_t)640 << 10); // 81 KiB: flags[8][64] + probe[8][64] + votes[8][32] + xcd_ctr[8], u32, 64B-padded
static constexpr size_t XF_OFF   = (size_t)16 << 20;                         // 64 MiB: xf f16 frag layout [t][g 8][kk 16][L 64] half8
static constexpr size_t WS_NEED  = XF_OFF + (size_t)T_ * B_ * E_ * 2;        // 80 MiB

__device__ __forceinline__ float fsigm(float x) { return 1.f / (1.f + __expf(-x)); }
__device__ __forceinline__ float ftanh(float x) {
  float cx = fminf(fmaxf(x, -15.f), 15.f);
  float e = __expf(2.f * cx);
  return (e - 1.f) / (e + 1.f);
}
__device__ __forceinline__ half8 as_h8(f32x4 x) {
  union { f32x4 f; half8 h; } u; u.f = x; return u.h;
}

// ---------------- diag: ws too small — encode ws MiB in out[0] ----------------
__global__ void k_diag(float* __restrict__ out, int n, unsigned wsmb) {
  int i = blockIdx.x * 256 + threadIdx.x;
  if (i < n) out[i] = (i == 0) ? (float)wsmb : 0.1f;
}

// ---------------- prep: frag-layout weights, zero h/flags ----------------
__global__ __launch_bounds__(256) void k_prep(
    const float* __restrict__ Wxi, const float* __restrict__ Wxf,
    const float* __restrict__ Wxo, const float* __restrict__ Wxc,
    const float* __restrict__ Whi, const float* __restrict__ Whf,
    const float* __restrict__ Who, const float* __restrict__ Whc,
    const float* __restrict__ bi, const float* __restrict__ bfp,
    const float* __restrict__ bo, const float* __restrict__ bc,
    char* __restrict__ ws) {
  half8* wx = (half8*)(ws + WX_OFF);
  half8* wh = (half8*)(ws + WH_OFF);
  float* bg = (float*)(ws + BG_OFF);
  half8* hb = (half8*)(ws + HBUF_OFF);
  unsigned* bar = (unsigned*)(ws + BAR_OFF);
  const float* WxA[4] = {Wxi, Wxf, Wxo, Wxc};
  const float* WhA[4] = {Whi, Whf, Who, Whc};
  const float* bA[4]  = {bi, bfp, bo, bc};

  const int ZWX = 256 * 16 * 64;      // 262144 frags
  const int ZWH = 32 * 8 * 32 * 64;   // 524288 frags
  const int ZBG = NG;
  const int ZHB = 2 * B_ * H_ / 8;    // 32768 half8
  const int ZBAR = 8 * 64 * 16 + 8 * 64 * 16 + 8 * 32 * 16 + 8 * 16;  // flags+probe+votes+ctr
  const int total = ZWX + ZWH + ZBG + ZHB + ZBAR;

  for (int it = blockIdx.x * 256 + threadIdx.x; it < total; it += gridDim.x * 256) {
    int i = it;
    if (i < ZWX) {
      // B-frag elem j = Wx_gate[k = kt*32 + quad*8 + j][col]; ntg = g*64 + hblk*2 + ct
      int L = i & 63, kt = (i >> 6) & 15, ntg = i >> 10;
      int gate = ntg >> 6;
      int col = ((ntg & 63) << 4) + (L & 15);
      int k0 = (kt << 5) + ((L >> 4) << 3);
      const float* src = WxA[gate] + (size_t)k0 * H_ + col;
      half8 v;
#pragma unroll
      for (int j = 0; j < 8; j++) v[j] = (_Float16)src[(size_t)j * H_];
      wx[i] = v;
    } else if ((i -= ZWX) < ZWH) {
      // layout [hbk 32][nt 8][kt 32][L 64]; nt = g*2+ct; col = hbk*32 + ct*16 + (L&15)
      int L = i & 63, kt = (i >> 6) & 31, nt = (i >> 11) & 7, hbk = i >> 14;
      int ct = nt & 1, g = nt >> 1;
      int col = (hbk << 5) + (ct << 4) + (L & 15);
      int k0 = (kt << 5) + ((L >> 4) << 3);
      const float* src = WhA[g] + (size_t)k0 * H_ + col;
      half8 v;
#pragma unroll
      for (int j = 0; j < 8; j++) v[j] = (_Float16)src[(size_t)j * H_];
      wh[i] = v;
    } else if ((i -= ZWH) < ZBG) {
      bg[i] = bA[i >> 10][i & 1023];
    } else if ((i -= ZBG) < ZHB) {
      half8 z = {};
      hb[i] = z;
    } else {
      i -= ZHB;
      bar[i] = 0u;
    }
  }
}

// ---------------- embed: xf in A-frag layout ----------------
// x[b][k] -> g=b>>4,row=b&15, kk=k>>5,q=(k>>3)&3,j=k&7 : xf[(t*8+g)*16+kk][row|(q<<4)][j]
__global__ __launch_bounds__(256) void k_embed(const int* __restrict__ ids,
                                               const float* __restrict__ emb,
                                               char* __restrict__ ws) {
  half8* xf = (half8*)(ws + XF_OFF);
  const int t = blockIdx.x;
  for (int p = threadIdx.x; p < 128 * 64; p += 256) {
    int b = p >> 6, c8 = p & 63;  // c8: which aligned 8-elem chunk of E (kk=c8>>2, q=c8&3)
    int id = ids[b * T_ + t];
    const float* er = emb + (size_t)id * E_ + (c8 << 3);
    float4 f0 = *(const float4*)er;
    float4 f1 = *(const float4*)(er + 4);
    half8 v;
    v[0] = (_Float16)f0.x; v[1] = (_Float16)f0.y; v[2] = (_Float16)f0.z; v[3] = (_Float16)f0.w;
    v[4] = (_Float16)f1.x; v[5] = (_Float16)f1.y; v[6] = (_Float16)f1.z; v[7] = (_Float16)f1.w;
    int g = b >> 4, row = b & 15;
    xf[((size_t)(t * 8 + g) * 16 + (c8 >> 2)) * 64 + (row | ((c8 & 3) << 4))] = v;
  }
}

// ---------------- fused persistent recurrence + input projection ----------------
// R6 structure (XCD-local groups by construction + bounded sc0 probe + agent fallback).
// R7: fast-path loop re-ordered for latency hiding —
//   (1) ah loads issue first; Wx MFMAs execute UNDER the ah flight; then vmcnt(0).
//   (2) ax(t+1) prefetch issued (pinned asm, same regs) BEFORE the Wh MFMAs:
//       covered by Wh+barrier+update/poll (~1500cy) instead of racing next-step use.
//   (3) hard-spin poll (no s_sleep): waves sit on separate SIMDs; polled lines are
//       read-shared in XCD L2 (no ownership ping-pong).
// Slow path: exact R6 agent-scope loop (proven).
__global__ __launch_bounds__(256, 1) void k_lstm(char* __restrict__ ws) {
  __shared__ f32x4 red[4][8][64];          // 32 KB
  __shared__ _Float16 hstage2[2][16][16];  // 1 KB: per-producer-wave transpose tile
  __shared__ unsigned red_ep[2];           // intra-WG "red consumed" epochs
  __shared__ int wok[4];                   // per-wave probe results
  __shared__ unsigned sslot, sbal;         // runtime role slot / balanced flag
  const half8* whf = (const half8*)(ws + WH_OFF);
  const half8* wxg = (const half8*)(ws + WX_OFF);
  const float* bgp = (const float*)(ws + BG_OFF);
  _Float16* hbuf = (_Float16*)(ws + HBUF_OFF);
  const half8* xff = (const half8*)(ws + XF_OFF);
  unsigned* bar = (unsigned*)(ws + BAR_OFF);

  const int wg = blockIdx.x;
  const int tid = threadIdx.x;
  const int L = tid & 63, w = tid >> 6;
  const int lo = L & 15, quad = L >> 4;
  unsigned* ctrp = bar + 20480;  // 8 xcd counters, 64B apart

  // ---- runtime role claim: group = my XCD, hblk = slot within it ----
  unsigned myxid;
  asm volatile("s_getreg_b32 %0, hwreg(HW_REG_XCC_ID)" : "=s"(myxid));
  myxid &= 7u;
  if (tid == 0)
    sslot = __hip_atomic_fetch_add(&ctrp[myxid * 16], 1u, __ATOMIC_RELAXED,
                                   __HIP_MEMORY_SCOPE_AGENT);
  __syncthreads();
  const unsigned slot = __builtin_amdgcn_readfirstlane(sslot);
  if (tid == 0) {
    // wait until all 256 WGs registered (terminates: co-resident grid), then check balance
    unsigned cnt[8];
    while (true) {
      unsigned s = 0;
#pragma unroll
      for (int x = 0; x < 8; x++) {
        cnt[x] = __hip_atomic_load(&ctrp[x * 16], __ATOMIC_RELAXED, __HIP_MEMORY_SCOPE_AGENT);
        s += cnt[x];
      }
      if (s == 256u) break;
      __builtin_amdgcn_s_sleep(4);
    }
    unsigned ok = 1u;
#pragma unroll
    for (int x = 0; x < 8; x++) ok &= (cnt[x] == 32u) ? 1u : 0u;
    sbal = ok;
  }
  __syncthreads();
  const bool balanced = sbal != 0u;
  const int group = balanced ? (int)myxid : (wg & 7);   // batches [group*16, +16)
  const int hblk  = balanced ? (int)slot  : (wg >> 3);  // h-cols [hblk*32, +32) x 4 gates
  const int hbase = hblk << 5;
  unsigned* flags = bar + group * 1024;          // 4KB/group: 64 producer flags, 64B apart
  unsigned* probe = bar + 8192 + group * 1024;   // 4KB/group: 64 probe tokens, 64B apart
  unsigned* votes = bar + 16384 + group * 512;   // 2KB/group: 32 WG votes, 64B apart

  // probe token: plain store (write-through L1 -> dirty in MY XCD's L2)
  if (balanced && w < 2 && L == 0) {
    unsigned one = 1u;
    unsigned* pp = &probe[((hblk << 1) + w) << 4];
    asm volatile("global_store_dword %0, %1, off" :: "v"(pp), "v"(one) : "memory");
  }

  // B-frags (register/AGPR-resident): Wh [nt][k8] for K chunk [w*256,+256)
  half8 bw[8][8];
#pragma unroll
  for (int nt = 0; nt < 8; nt++)
#pragma unroll
    for (int k8 = 0; k8 < 8; k8++)
      bw[nt][k8] = whf[((size_t)(hblk * 8 + nt) * 32 + w * 8 + k8) * 64 + L];
  // Wx [nt][kx] for K chunk [w*128,+128); ntg = g*64 + hblk*2 + ct, nt = g*2+ct
  half8 wxr[8][4];
#pragma unroll
  for (int nt = 0; nt < 8; nt++)
#pragma unroll
    for (int kx = 0; kx < 4; kx++)
      wxr[nt][kx] =
          wxg[(size_t)(((nt >> 1) * 64 + (hblk << 1) + (nt & 1)) * 16 + w * 4 + kx) * 64 + L];

  // ---- bounded behavioral probe of the sc0-load/plain-store exchange ----
  bool fast = false;
  if (balanced) {
    int okw = 0;
    for (int it = 0; it < 1500 && !okw; ++it) {
      unsigned v = 1u;
      if (L < 16) {
        const unsigned* pp = &probe[(w * 16 + L) << 4];
        unsigned vv;
        asm volatile("global_load_dword %0, %1, off sc0 nt\n\ts_waitcnt vmcnt(0)"
                     : "=v"(vv) : "v"(pp) : "memory");
        v = vv;
      }
      okw = __all((int)(v != 0u));
      if (!okw) __builtin_amdgcn_s_sleep(2);
    }
    if (L == 0) wok[w] = okw;
    __syncthreads();
    const int allok = wok[0] & wok[1] & wok[2] & wok[3];
    if (tid == 0)
      __hip_atomic_store(&votes[hblk << 4], (unsigned)(allok ? 2 : 1),
                         __ATOMIC_RELAXED, __HIP_MEMORY_SCOPE_AGENT);
    unsigned fastu;
    while (true) {
      unsigned v = 2u;
      if (L < 32)
        v = __hip_atomic_load(&votes[L << 4], __ATOMIC_RELAXED, __HIP_MEMORY_SCOPE_AGENT);
      if (__all((int)(v != 0u))) { fastu = (unsigned)__all((int)(v == 2u)); break; }
      __builtin_amdgcn_s_sleep(8);
    }
    fast = fastu != 0;
  }

  float bgr[4] = {};
  f32x4 cst = {};
  if (w < 2) {  // update lanes: ct = w; (b = group*16 + quad*4 + r, col = hbase + w*16 + lo)
#pragma unroll
    for (int g = 0; g < 4; g++) bgr[g] = bgp[g * H_ + hbase + (w << 4) + lo];
  }
  if (tid < 2) red_ep[tid] = 0u;

  // preload ax (frag layout, plain cached loads) for t=0
  half8 ax[4];
  {
    const half8* xb = xff + (size_t)group * (16 * 64);
#pragma unroll
    for (int kx = 0; kx < 4; kx++) ax[kx] = xb[(w * 4 + kx) * 64 + L];
  }
  __syncthreads();

  if (fast) {
    // ================== FAST LOOP (XCD-local, latency-hidden) ==================
    for (int t = 0; t < T_; t++) {
      const _Float16* hb = hbuf + (size_t)(t & 1) * (B_ * H_);
      _Float16* hw = hbuf + (size_t)((t + 1) & 1) * (B_ * H_);

      // (1) issue 8 ah loads (sc0 nt: L1-bypass, XCD-L2-served)
      f32x4 ahf[8];
      const _Float16* hbp =
          hb + (((size_t)group * 32 + (size_t)(w * 8)) << 9) + ((size_t)L << 3);
      const _Float16* hbp2 = hbp + ((size_t)4 << 9);
      asm volatile("global_load_dwordx4 %0, %1, off sc0 nt"             : "=v"(ahf[0]) : "v"(hbp));
      asm volatile("global_load_dwordx4 %0, %1, off offset:1024 sc0 nt" : "=v"(ahf[1]) : "v"(hbp));
      asm volatile("global_load_dwordx4 %0, %1, off offset:2048 sc0 nt" : "=v"(ahf[2]) : "v"(hbp));
      asm volatile("global_load_dwordx4 %0, %1, off offset:3072 sc0 nt" : "=v"(ahf[3]) : "v"(hbp));
      asm volatile("global_load_dwordx4 %0, %1, off sc0 nt"             : "=v"(ahf[4]) : "v"(hbp2));
      asm volatile("global_load_dwordx4 %0, %1, off offset:1024 sc0 nt" : "=v"(ahf[5]) : "v"(hbp2));
      asm volatile("global_load_dwordx4 %0, %1, off offset:2048 sc0 nt" : "=v"(ahf[6]) : "v"(hbp2));
      asm volatile("global_load_dwordx4 %0, %1, off offset:3072 sc0 nt" : "=v"(ahf[7]) : "v"(hbp2));

      // (2) 32 Wx MFMAs on current ax — execute under the ah flight
      f32x4 acc[8] = {};
#pragma unroll
      for (int kx = 0; kx < 4; kx++)
#pragma unroll
        for (int nt = 0; nt < 8; nt++)
          acc[nt] = __builtin_amdgcn_mfma_f32_16x16x32_f16(ax[kx], wxr[nt][kx], acc[nt], 0, 0, 0);

      // (3) ah arrival gate (nothing else outstanding at this point)
      asm volatile("s_waitcnt vmcnt(0)" ::: "memory");
      __builtin_amdgcn_sched_barrier(0);  // rule #18: keep Wh MFMAs below the wait

      // (4) ax(t+1) prefetch — pinned asm into the SAME regs (WAR after Wx MFMAs);
      //     ~1500cy of Wh+barrier+update/poll cover its HBM/L3 latency
      {
        int tn = (t + 1 < T_) ? (t + 1) : t;
        const half8* xb = xff + (((size_t)tn * 8 + group) * (16 * 64)) + L;
        asm volatile("global_load_dwordx4 %0, %1, off"              : "=v"(ax[0]) : "v"(xb + (w * 4 + 0) * 64));
        asm volatile("global_load_dwordx4 %0, %1, off"              : "=v"(ax[1]) : "v"(xb + (w * 4 + 1) * 64));
        asm volatile("global_load_dwordx4 %0, %1, off"              : "=v"(ax[2]) : "v"(xb + (w * 4 + 2) * 64));
        asm volatile("global_load_dwordx4 %0, %1, off"              : "=v"(ax[3]) : "v"(xb + (w * 4 + 3) * 64));
      }
      __builtin_amdgcn_sched_barrier(0);  // pin: ax issue stays above the Wh block

      // (5) 64 Wh MFMAs
#pragma unroll
      for (int k8 = 0; k8 < 8; k8++)
#pragma unroll
        for (int nt = 0; nt < 8; nt++)
          acc[nt] = __builtin_amdgcn_mfma_f32_16x16x32_f16(as_h8(ahf[k8]), bw[nt][k8], acc[nt], 0, 0, 0);
#pragma unroll
      for (int nt = 0; nt < 8; nt++) red[w][nt][L] = acc[nt];
      __syncthreads();  // sync1: the ONLY per-step barrier (K-partials exchanged)

      if (w < 2) {
        // reduce partials
        f32x4 gv[4];
#pragma unroll
        for (int g = 0; g < 4; g++) {
          f32x4 s = red[0][g * 2 + w][L];
          s += red[1][g * 2 + w][L];
          s += red[2][g * 2 + w][L];
          s += red[3][g * 2 + w][L];
          gv[g] = s;
        }
        // signal red consumed (LDS, release)
        if (L == 0)
          __hip_atomic_store(&red_ep[w], (unsigned)(t + 1), __ATOMIC_RELEASE,
                             __HIP_MEMORY_SCOPE_WORKGROUP);
        // gate math
#pragma unroll
        for (int r = 0; r < 4; r++) {
          float gi = gv[0][r] + bgr[0];
          float gf = gv[1][r] + bgr[1];
          float go = gv[2][r] + bgr[2];
          float gc = gv[3][r] + bgr[3];
          float c = fsigm(gf) * cst[r] + fsigm(gi) * ftanh(gc);
          cst[r] = c;
          hstage2[w][(quad << 2) + r][lo] = (_Float16)(fsigm(go) * ftanh(c));
        }
        // intra-wave transpose readback -> frag layout
        __builtin_amdgcn_wave_barrier();
        asm volatile("s_waitcnt lgkmcnt(0)" ::: "memory");
        int rrow = (L >> 1) & 15;
        int cb = ((L >> 5) << 3) + ((L & 1) << 2);
        union { _Float16 h[4]; unsigned long long u; } sv;
#pragma unroll
        for (int q = 0; q < 4; q++) sv.h[q] = hstage2[w][rrow][cb + q];
        unsigned long long* dp =
            (unsigned long long*)(hw + (((size_t)(group * 32 + hblk)) << 9) +
                                  ((size_t)w << 8) + ((size_t)L << 2));
        unsigned* fptr = &flags[((hblk << 1) + w) << 4];
        unsigned ep = (unsigned)(t + 1);
        // plain stores: write-through L1 -> dirty in XCD L2; no fabric crossing
        asm volatile("global_store_dwordx2 %0, %1, off" :: "v"(dp), "v"(sv.u) : "memory");
        asm volatile("s_waitcnt vmcnt(0)" ::: "memory");  // h (and ax) committed before flag
        if (L == 0)
          asm volatile("global_store_dword %0, %1, off" :: "v"(fptr), "v"(ep) : "memory");
      }

      if (t + 1 < T_) {
        const unsigned tgt = (unsigned)(t + 1);
        // hard-spin poll: exactly the 16 h-producer flags of my K chunk
        const unsigned* fp16 = &flags[(w * 16 + (L & 15)) << 4];
        while (true) {
          unsigned v = tgt;
          if (L < 16) {
            unsigned vv;
            asm volatile("global_load_dword %0, %1, off sc0 nt\n\ts_waitcnt vmcnt(0)"
                         : "=v"(vv) : "v"(fp16) : "memory");
            v = vv;
          }
          if (__all((int)(v >= tgt))) break;
        }
        // intra-WG: red consumed by both producer waves (LDS, nearly always ready)
        while (true) {
          unsigned v = tgt;
          if (L < 2)
            v = __hip_atomic_load(&red_ep[L], __ATOMIC_ACQUIRE, __HIP_MEMORY_SCOPE_WORKGROUP);
          if (__all((int)(v >= tgt))) break;
        }
        __builtin_amdgcn_sched_barrier(0);  // pin: next-step ah loads issue after poll
      }
    }
  } else {
    // ================== SLOW LOOP (exact R6 agent-scope protocol) ==================
    for (int t = 0; t < T_; t++) {
      const _Float16* hb = hbuf + (size_t)(t & 1) * (B_ * H_);
      _Float16* hw = hbuf + (size_t)((t + 1) & 1) * (B_ * H_);

      f32x4 ahf[8];
      const _Float16* hbp =
          hb + (((size_t)group * 32 + (size_t)(w * 8)) << 9) + ((size_t)L << 3);
#pragma unroll
      for (int k8 = 0; k8 < 8; k8++) {
        const unsigned long long* ap = (const unsigned long long*)(hbp + ((size_t)k8 << 9));
        union { unsigned long long u[2]; f32x4 f; } cv;
        cv.u[0] = __hip_atomic_load(ap, __ATOMIC_RELAXED, __HIP_MEMORY_SCOPE_AGENT);
        cv.u[1] = __hip_atomic_load(ap + 1, __ATOMIC_RELAXED, __HIP_MEMORY_SCOPE_AGENT);
        ahf[k8] = cv.f;
      }

      f32x4 acc[8] = {};
#pragma unroll
      for (int kx = 0; kx < 4; kx++)
#pragma unroll
        for (int nt = 0; nt < 8; nt++)
          acc[nt] = __builtin_amdgcn_mfma_f32_16x16x32_f16(ax[kx], wxr[nt][kx], acc[nt], 0, 0, 0);
#pragma unroll
      for (int k8 = 0; k8 < 8; k8++)
#pragma unroll
        for (int nt = 0; nt < 8; nt++)
          acc[nt] = __builtin_amdgcn_mfma_f32_16x16x32_f16(as_h8(ahf[k8]), bw[nt][k8], acc[nt], 0, 0, 0);
#pragma unroll
      for (int nt = 0; nt < 8; nt++) red[w][nt][L] = acc[nt];
      __syncthreads();

      if (w < 2) {
        f32x4 gv[4];
#pragma unroll
        for (int g = 0; g < 4; g++) {
          f32x4 s = red[0][g * 2 + w][L];
          s += red[1][g * 2 + w][L];
          s += red[2][g * 2 + w][L];
          s += red[3][g * 2 + w][L];
          gv[g] = s;
        }
        if (L == 0)
          __hip_atomic_store(&red_ep[w], (unsigned)(t + 1), __ATOMIC_RELEASE,
                             __HIP_MEMORY_SCOPE_WORKGROUP);
#pragma unroll
        for (int r = 0; r < 4; r++) {
          float gi = gv[0][r] + bgr[0];
          float gf = gv[1][r] + bgr[1];
          float go = gv[2][r] + bgr[2];
          float gc = gv[3][r] + bgr[3];
          float c = fsigm(gf) * cst[r] + fsigm(gi) * ftanh(gc);
          cst[r] = c;
          hstage2[w][(quad << 2) + r][lo] = (_Float16)(fsigm(go) * ftanh(c));
        }
        __builtin_amdgcn_wave_barrier();
        asm volatile("s_waitcnt lgkmcnt(0)" ::: "memory");
        int rrow = (L >> 1) & 15;
        int cb = ((L >> 5) << 3) + ((L & 1) << 2);
        union { _Float16 h[4]; unsigned long long u; } sv;
#pragma unroll
        for (int q = 0; q < 4; q++) sv.h[q] = hstage2[w][rrow][cb + q];
        unsigned long long* dp =
            (unsigned long long*)(hw + (((size_t)(group * 32 + hblk)) << 9) +
                                  ((size_t)w << 8) + ((size_t)L << 2));
        unsigned* fptr = &flags[((hblk << 1) + w) << 4];
        unsigned ep = (unsigned)(t + 1);
        __hip_atomic_store(dp, sv.u, __ATOMIC_RELAXED, __HIP_MEMORY_SCOPE_AGENT);
        asm volatile("s_waitcnt vmcnt(0)" ::: "memory");
        if (L == 0)
          __hip_atomic_store(fptr, ep, __ATOMIC_RELAXED, __HIP_MEMORY_SCOPE_AGENT);
      }

      {
        int tn = (t + 1 < T_) ? (t + 1) : t;
        const half8* xb = xff + ((size_t)tn * 8 + group) * (16 * 64);
#pragma unroll
        for (int kx = 0; kx < 4; kx++) ax[kx] = xb[(w * 4 + kx) * 64 + L];
      }

      if (t + 1 < T_) {
        const unsigned tgt = (unsigned)(t + 1);
        while (true) {
          unsigned v = tgt;
          if (L < 16)
            v = __hip_atomic_load(&flags[(w * 16 + L) << 4], __ATOMIC_RELAXED,
                                  __HIP_MEMORY_SCOPE_AGENT);
          if (__all((int)(v >= tgt))) break;
          __builtin_amdgcn_s_sleep(1);
        }
        while (true) {
          unsigned v = tgt;
          if (L < 2)
            v = __hip_atomic_load(&red_ep[L], __ATOMIC_ACQUIRE, __HIP_MEMORY_SCOPE_WORKGROUP);
          if (__all((int)(v >= tgt))) break;
        }
        __builtin_amdgcn_sched_barrier(0);
      }
    }
  }
}

// ---------------- final: softmax(h @ W_hq + b_q), h in frag layout ----------------
__global__ __launch_bounds__(64) void k_final(const char* __restrict__ ws,
                                              const float* __restrict__ Whq,
                                              const float* __restrict__ bq,
                                              float* __restrict__ out) {
  const int b = blockIdx.x;
  const int l = threadIdx.x;
  const _Float16* hf = (const _Float16*)(ws + HBUF_OFF);  // h_512 in buf 0 (T even)
  const int g = b >> 4, row = b & 15;
  float s[10];
#pragma unroll
  for (int o = 0; o < 10; o++) s[o] = 0.f;
  for (int k = l; k < H_; k += 64) {
    int kk = k >> 5, q = (k >> 3) & 3, j = k & 7;
    float hv = (float)hf[(((size_t)g * 32 + kk) * 64 + (row | (q << 4))) * 8 + j];
    const float* wr = Whq + (size_t)k * 10;
#pragma unroll
    for (int o = 0; o < 10; o++) s[o] += hv * wr[o];
  }
#pragma unroll
  for (int o = 0; o < 10; o++) {
#pragma unroll
    for (int d = 32; d > 0; d >>= 1) s[o] += __shfl_down(s[o], d);
  }
  if (l == 0) {
    float mx = -1e30f;
    for (int o = 0; o < 10; o++) { s[o] += bq[o]; mx = fmaxf(mx, s[o]); }
    float ssum = 0.f, ex[10];
    for (int o = 0; o < 10; o++) { ex[o] = __expf(s[o] - mx); ssum += ex[o]; }
    for (int o = 0; o < 10; o++) out[b * 10 + o] = ex[o] / ssum;
  }
}

extern "C" void kernel_launch(void* const* d_in, const int* in_sizes, int n_in,
                              void* d_out, int out_size, void* d_ws, size_t ws_size,
                              hipStream_t stream) {
  const int* ids   = (const int*)d_in[0];
  const float* emb = (const float*)d_in[1];
  const float* Wxi = (const float*)d_in[2];
  const float* Whi = (const float*)d_in[3];
  const float* bi  = (const float*)d_in[4];
  const float* Wxf = (const float*)d_in[5];
  const float* Whf = (const float*)d_in[6];
  const float* bfv = (const float*)d_in[7];
  const float* Wxo = (const float*)d_in[8];
  const float* Who = (const float*)d_in[9];
  const float* bo  = (const float*)d_in[10];
  const float* Wxc = (const float*)d_in[11];
  const float* Whc = (const float*)d_in[12];
  const float* bc  = (const float*)d_in[13];
  const float* Whq = (const float*)d_in[14];
  const float* bq  = (const float*)d_in[15];
  float* out = (float*)d_out;
  char* ws = (char*)d_ws;

  if (ws_size < WS_NEED) {
    k_diag<<<(out_size + 255) / 256, 256, 0, stream>>>(out, out_size, (unsigned)(ws_size >> 20));
    return;
  }

  k_prep<<<3217, 256, 0, stream>>>(Wxi, Wxf, Wxo, Wxc, Whi, Whf, Who, Whc, bi, bfv, bo, bc, ws);
  k_embed<<<512, 256, 0, stream>>>(ids, emb, ws);
  k_lstm<<<256, 256, 0, stream>>>(ws);
  k_final<<<128, 64, 0, stream>>>(ws, Whq, bq, out);
}

// Round 8
// 1912.126 us; speedup vs baseline: 1.0689x; 1.0689x over previous
//
#include <hip/hip_runtime.h>
#include <hip/hip_fp16.h>

#define V_ 50000
#define E_ 512
#define H_ 1024
#define B_ 128
#define T_ 512
#define NG 4096  // 4*H

typedef _Float16 half8 __attribute__((ext_vector_type(8)));
typedef float f32x4 __attribute__((ext_vector_type(4)));

// ---- workspace layout (bytes) ----
static constexpr size_t WX_OFF   = 0;                                        // 4 MiB: Wx f16 B-frags [ntg 256][kt 16][L 64] half8
static constexpr size_t WH_OFF   = (size_t)4 << 20;                          // 8 MiB: Wh f16 B-frags [hblk 32][nt 8][kt 32][L 64] half8
static constexpr size_t BG_OFF   = (size_t)12 << 20;                         // 16 KiB: bias concat f32 [4096]
static constexpr size_t HBUF_OFF = ((size_t)12 << 20) + ((size_t)64 << 10);  // 512 KiB: h dbuf [2][g 8][kk 32][L 64] half8 (A-frag layout)
static constexpr size_t BAR_OFF  = ((size_t)12 << 20) + ((size_t)640 << 10); // 81 KiB: flags[8][64] + probe[8][64] + votes[8][32] + xcd_ctr[8], u32, 64B-padded
static constexpr size_t XF_OFF   = (size_t)16 << 20;                         // 64 MiB: xf f16 frag layout [t][g 8][kk 16][L 64] half8
static constexpr size_t WS_NEED  = XF_OFF + (size_t)T_ * B_ * E_ * 2;        // 80 MiB

__device__ __forceinline__ float fsigm(float x) { return 1.f / (1.f + __expf(-x)); }
__device__ __forceinline__ float ftanh(float x) {
  float cx = fminf(fmaxf(x, -15.f), 15.f);
  float e = __expf(2.f * cx);
  return (e - 1.f) / (e + 1.f);
}
__device__ __forceinline__ half8 as_h8(f32x4 x) {
  union { f32x4 f; half8 h; } u; u.f = x; return u.h;
}

// ---------------- diag: ws too small — encode ws MiB in out[0] ----------------
__global__ void k_diag(float* __restrict__ out, int n, unsigned wsmb) {
  int i = blockIdx.x * 256 + threadIdx.x;
  if (i < n) out[i] = (i == 0) ? (float)wsmb : 0.1f;
}

// ---------------- prep: frag-layout weights, zero h/flags ----------------
__global__ __launch_bounds__(256) void k_prep(
    const float* __restrict__ Wxi, const float* __restrict__ Wxf,
    const float* __restrict__ Wxo, const float* __restrict__ Wxc,
    const float* __restrict__ Whi, const float* __restrict__ Whf,
    const float* __restrict__ Who, const float* __restrict__ Whc,
    const float* __restrict__ bi, const float* __restrict__ bfp,
    const float* __restrict__ bo, const float* __restrict__ bc,
    char* __restrict__ ws) {
  half8* wx = (half8*)(ws + WX_OFF);
  half8* wh = (half8*)(ws + WH_OFF);
  float* bg = (float*)(ws + BG_OFF);
  half8* hb = (half8*)(ws + HBUF_OFF);
  unsigned* bar = (unsigned*)(ws + BAR_OFF);
  const float* WxA[4] = {Wxi, Wxf, Wxo, Wxc};
  const float* WhA[4] = {Whi, Whf, Who, Whc};
  const float* bA[4]  = {bi, bfp, bo, bc};

  const int ZWX = 256 * 16 * 64;      // 262144 frags
  const int ZWH = 32 * 8 * 32 * 64;   // 524288 frags
  const int ZBG = NG;
  const int ZHB = 2 * B_ * H_ / 8;    // 32768 half8
  const int ZBAR = 8 * 64 * 16 + 8 * 64 * 16 + 8 * 32 * 16 + 8 * 16;  // flags+probe+votes+ctr
  const int total = ZWX + ZWH + ZBG + ZHB + ZBAR;

  for (int it = blockIdx.x * 256 + threadIdx.x; it < total; it += gridDim.x * 256) {
    int i = it;
    if (i < ZWX) {
      // B-frag elem j = Wx_gate[k = kt*32 + quad*8 + j][col]; ntg = g*64 + hblk*2 + ct
      int L = i & 63, kt = (i >> 6) & 15, ntg = i >> 10;
      int gate = ntg >> 6;
      int col = ((ntg & 63) << 4) + (L & 15);
      int k0 = (kt << 5) + ((L >> 4) << 3);
      const float* src = WxA[gate] + (size_t)k0 * H_ + col;
      half8 v;
#pragma unroll
      for (int j = 0; j < 8; j++) v[j] = (_Float16)src[(size_t)j * H_];
      wx[i] = v;
    } else if ((i -= ZWX) < ZWH) {
      // layout [hbk 32][nt 8][kt 32][L 64]; nt = g*2+ct; col = hbk*32 + ct*16 + (L&15)
      int L = i & 63, kt = (i >> 6) & 31, nt = (i >> 11) & 7, hbk = i >> 14;
      int ct = nt & 1, g = nt >> 1;
      int col = (hbk << 5) + (ct << 4) + (L & 15);
      int k0 = (kt << 5) + ((L >> 4) << 3);
      const float* src = WhA[g] + (size_t)k0 * H_ + col;
      half8 v;
#pragma unroll
      for (int j = 0; j < 8; j++) v[j] = (_Float16)src[(size_t)j * H_];
      wh[i] = v;
    } else if ((i -= ZWH) < ZBG) {
      bg[i] = bA[i >> 10][i & 1023];
    } else if ((i -= ZBG) < ZHB) {
      half8 z = {};
      hb[i] = z;
    } else {
      i -= ZHB;
      bar[i] = 0u;
    }
  }
}

// ---------------- embed: xf in A-frag layout ----------------
// x[b][k] -> g=b>>4,row=b&15, kk=k>>5,q=(k>>3)&3,j=k&7 : xf[(t*8+g)*16+kk][row|(q<<4)][j]
__global__ __launch_bounds__(256) void k_embed(const int* __restrict__ ids,
                                               const float* __restrict__ emb,
                                               char* __restrict__ ws) {
  half8* xf = (half8*)(ws + XF_OFF);
  const int t = blockIdx.x;
  for (int p = threadIdx.x; p < 128 * 64; p += 256) {
    int b = p >> 6, c8 = p & 63;  // c8: which aligned 8-elem chunk of E (kk=c8>>2, q=c8&3)
    int id = ids[b * T_ + t];
    const float* er = emb + (size_t)id * E_ + (c8 << 3);
    float4 f0 = *(const float4*)er;
    float4 f1 = *(const float4*)(er + 4);
    half8 v;
    v[0] = (_Float16)f0.x; v[1] = (_Float16)f0.y; v[2] = (_Float16)f0.z; v[3] = (_Float16)f0.w;
    v[4] = (_Float16)f1.x; v[5] = (_Float16)f1.y; v[6] = (_Float16)f1.z; v[7] = (_Float16)f1.w;
    int g = b >> 4, row = b & 15;
    xf[((size_t)(t * 8 + g) * 16 + (c8 >> 2)) * 64 + (row | ((c8 & 3) << 4))] = v;
  }
}

// ---------------- fused persistent recurrence + input projection ----------------
// R6 structure (XCD-local groups by construction + bounded sc0 probe + agent fallback).
// R8 = R6 loop with ONE change (R7 isolated the harmful edits: mid-loop ax prefetch in
// the producer drain window, and hard-spin poll — both reverted):
//   the 32 Wx MFMAs now execute UNDER the 8 ah loads' flight; vmcnt(0)+sched_barrier
//   then gates the Wh MFMAs (rule #18). ax prefetch stays AFTER the producer flag
//   store (never inside the drain); poll keeps s_sleep(1).
__global__ __launch_bounds__(256, 1) void k_lstm(char* __restrict__ ws) {
  __shared__ f32x4 red[4][8][64];          // 32 KB
  __shared__ _Float16 hstage2[2][16][16];  // 1 KB: per-producer-wave transpose tile
  __shared__ unsigned red_ep[2];           // intra-WG "red consumed" epochs
  __shared__ int wok[4];                   // per-wave probe results
  __shared__ unsigned sslot, sbal;         // runtime role slot / balanced flag
  const half8* whf = (const half8*)(ws + WH_OFF);
  const half8* wxg = (const half8*)(ws + WX_OFF);
  const float* bgp = (const float*)(ws + BG_OFF);
  _Float16* hbuf = (_Float16*)(ws + HBUF_OFF);
  const half8* xff = (const half8*)(ws + XF_OFF);
  unsigned* bar = (unsigned*)(ws + BAR_OFF);

  const int wg = blockIdx.x;
  const int tid = threadIdx.x;
  const int L = tid & 63, w = tid >> 6;
  const int lo = L & 15, quad = L >> 4;
  unsigned* ctrp = bar + 20480;  // 8 xcd counters, 64B apart

  // ---- runtime role claim: group = my XCD, hblk = slot within it ----
  unsigned myxid;
  asm volatile("s_getreg_b32 %0, hwreg(HW_REG_XCC_ID)" : "=s"(myxid));
  myxid &= 7u;
  if (tid == 0)
    sslot = __hip_atomic_fetch_add(&ctrp[myxid * 16], 1u, __ATOMIC_RELAXED,
                                   __HIP_MEMORY_SCOPE_AGENT);
  __syncthreads();
  const unsigned slot = __builtin_amdgcn_readfirstlane(sslot);
  if (tid == 0) {
    // wait until all 256 WGs registered (terminates: co-resident grid), then check balance
    unsigned cnt[8];
    while (true) {
      unsigned s = 0;
#pragma unroll
      for (int x = 0; x < 8; x++) {
        cnt[x] = __hip_atomic_load(&ctrp[x * 16], __ATOMIC_RELAXED, __HIP_MEMORY_SCOPE_AGENT);
        s += cnt[x];
      }
      if (s == 256u) break;
      __builtin_amdgcn_s_sleep(4);
    }
    unsigned ok = 1u;
#pragma unroll
    for (int x = 0; x < 8; x++) ok &= (cnt[x] == 32u) ? 1u : 0u;
    sbal = ok;
  }
  __syncthreads();
  const bool balanced = sbal != 0u;
  const int group = balanced ? (int)myxid : (wg & 7);   // batches [group*16, +16)
  const int hblk  = balanced ? (int)slot  : (wg >> 3);  // h-cols [hblk*32, +32) x 4 gates
  const int hbase = hblk << 5;
  unsigned* flags = bar + group * 1024;          // 4KB/group: 64 producer flags, 64B apart
  unsigned* probe = bar + 8192 + group * 1024;   // 4KB/group: 64 probe tokens, 64B apart
  unsigned* votes = bar + 16384 + group * 512;   // 2KB/group: 32 WG votes, 64B apart

  // probe token: plain store (write-through L1 -> dirty in MY XCD's L2)
  if (balanced && w < 2 && L == 0) {
    unsigned one = 1u;
    unsigned* pp = &probe[((hblk << 1) + w) << 4];
    asm volatile("global_store_dword %0, %1, off" :: "v"(pp), "v"(one) : "memory");
  }

  // B-frags (register/AGPR-resident): Wh [nt][k8] for K chunk [w*256,+256)
  half8 bw[8][8];
#pragma unroll
  for (int nt = 0; nt < 8; nt++)
#pragma unroll
    for (int k8 = 0; k8 < 8; k8++)
      bw[nt][k8] = whf[((size_t)(hblk * 8 + nt) * 32 + w * 8 + k8) * 64 + L];
  // Wx [nt][kx] for K chunk [w*128,+128); ntg = g*64 + hblk*2 + ct, nt = g*2+ct
  half8 wxr[8][4];
#pragma unroll
  for (int nt = 0; nt < 8; nt++)
#pragma unroll
    for (int kx = 0; kx < 4; kx++)
      wxr[nt][kx] =
          wxg[(size_t)(((nt >> 1) * 64 + (hblk << 1) + (nt & 1)) * 16 + w * 4 + kx) * 64 + L];

  // ---- bounded behavioral probe of the sc0-load/plain-store exchange ----
  bool fast = false;
  if (balanced) {
    int okw = 0;
    for (int it = 0; it < 1500 && !okw; ++it) {
      unsigned v = 1u;
      if (L < 16) {
        const unsigned* pp = &probe[(w * 16 + L) << 4];
        unsigned vv;
        asm volatile("global_load_dword %0, %1, off sc0 nt\n\ts_waitcnt vmcnt(0)"
                     : "=v"(vv) : "v"(pp) : "memory");
        v = vv;
      }
      okw = __all((int)(v != 0u));
      if (!okw) __builtin_amdgcn_s_sleep(2);
    }
    if (L == 0) wok[w] = okw;
    __syncthreads();
    const int allok = wok[0] & wok[1] & wok[2] & wok[3];
    if (tid == 0)
      __hip_atomic_store(&votes[hblk << 4], (unsigned)(allok ? 2 : 1),
                         __ATOMIC_RELAXED, __HIP_MEMORY_SCOPE_AGENT);
    unsigned fastu;
    while (true) {
      unsigned v = 2u;
      if (L < 32)
        v = __hip_atomic_load(&votes[L << 4], __ATOMIC_RELAXED, __HIP_MEMORY_SCOPE_AGENT);
      if (__all((int)(v != 0u))) { fastu = (unsigned)__all((int)(v == 2u)); break; }
      __builtin_amdgcn_s_sleep(8);
    }
    fast = fastu != 0;
  }

  float bgr[4] = {};
  f32x4 cst = {};
  if (w < 2) {  // update lanes: ct = w; (b = group*16 + quad*4 + r, col = hbase + w*16 + lo)
#pragma unroll
    for (int g = 0; g < 4; g++) bgr[g] = bgp[g * H_ + hbase + (w << 4) + lo];
  }
  if (tid < 2) red_ep[tid] = 0u;

  // preload ax (frag layout, plain cached loads) for t=0
  half8 ax[4];
  {
    const half8* xb = xff + (size_t)group * (16 * 64);
#pragma unroll
    for (int kx = 0; kx < 4; kx++) ax[kx] = xb[(w * 4 + kx) * 64 + L];
  }
  __syncthreads();

  if (fast) {
    // ================== FAST LOOP (XCD-local; Wx MFMAs under ah flight) ==================
    for (int t = 0; t < T_; t++) {
      const _Float16* hb = hbuf + (size_t)(t & 1) * (B_ * H_);
      _Float16* hw = hbuf + (size_t)((t + 1) & 1) * (B_ * H_);

      // (1) issue 8 ah loads (sc0 nt: L1-bypass, XCD-L2-served)
      f32x4 ahf[8];
      const _Float16* hbp =
          hb + (((size_t)group * 32 + (size_t)(w * 8)) << 9) + ((size_t)L << 3);
      const _Float16* hbp2 = hbp + ((size_t)4 << 9);
      asm volatile("global_load_dwordx4 %0, %1, off sc0 nt"             : "=v"(ahf[0]) : "v"(hbp));
      asm volatile("global_load_dwordx4 %0, %1, off offset:1024 sc0 nt" : "=v"(ahf[1]) : "v"(hbp));
      asm volatile("global_load_dwordx4 %0, %1, off offset:2048 sc0 nt" : "=v"(ahf[2]) : "v"(hbp));
      asm volatile("global_load_dwordx4 %0, %1, off offset:3072 sc0 nt" : "=v"(ahf[3]) : "v"(hbp));
      asm volatile("global_load_dwordx4 %0, %1, off sc0 nt"             : "=v"(ahf[4]) : "v"(hbp2));
      asm volatile("global_load_dwordx4 %0, %1, off offset:1024 sc0 nt" : "=v"(ahf[5]) : "v"(hbp2));
      asm volatile("global_load_dwordx4 %0, %1, off offset:2048 sc0 nt" : "=v"(ahf[6]) : "v"(hbp2));
      asm volatile("global_load_dwordx4 %0, %1, off offset:3072 sc0 nt" : "=v"(ahf[7]) : "v"(hbp2));

      // (2) 32 Wx MFMAs on current ax — execute under the ah flight
      f32x4 acc[8] = {};
#pragma unroll
      for (int kx = 0; kx < 4; kx++)
#pragma unroll
        for (int nt = 0; nt < 8; nt++)
          acc[nt] = __builtin_amdgcn_mfma_f32_16x16x32_f16(ax[kx], wxr[nt][kx], acc[nt], 0, 0, 0);

      // (3) ah arrival gate; keep Wh MFMAs below (rule #18)
      asm volatile("s_waitcnt vmcnt(0)" ::: "memory");
      __builtin_amdgcn_sched_barrier(0);

      // (4) 64 Wh MFMAs
#pragma unroll
      for (int k8 = 0; k8 < 8; k8++)
#pragma unroll
        for (int nt = 0; nt < 8; nt++)
          acc[nt] = __builtin_amdgcn_mfma_f32_16x16x32_f16(as_h8(ahf[k8]), bw[nt][k8], acc[nt], 0, 0, 0);
#pragma unroll
      for (int nt = 0; nt < 8; nt++) red[w][nt][L] = acc[nt];
      __syncthreads();  // sync1: the ONLY per-step barrier (K-partials exchanged)

      if (w < 2) {
        // reduce partials
        f32x4 gv[4];
#pragma unroll
        for (int g = 0; g < 4; g++) {
          f32x4 s = red[0][g * 2 + w][L];
          s += red[1][g * 2 + w][L];
          s += red[2][g * 2 + w][L];
          s += red[3][g * 2 + w][L];
          gv[g] = s;
        }
        // signal red consumed (LDS, release)
        if (L == 0)
          __hip_atomic_store(&red_ep[w], (unsigned)(t + 1), __ATOMIC_RELEASE,
                             __HIP_MEMORY_SCOPE_WORKGROUP);
        // gate math
#pragma unroll
        for (int r = 0; r < 4; r++) {
          float gi = gv[0][r] + bgr[0];
          float gf = gv[1][r] + bgr[1];
          float go = gv[2][r] + bgr[2];
          float gc = gv[3][r] + bgr[3];
          float c = fsigm(gf) * cst[r] + fsigm(gi) * ftanh(gc);
          cst[r] = c;
          hstage2[w][(quad << 2) + r][lo] = (_Float16)(fsigm(go) * ftanh(c));
        }
        // intra-wave transpose readback -> frag layout
        __builtin_amdgcn_wave_barrier();
        asm volatile("s_waitcnt lgkmcnt(0)" ::: "memory");
        int rrow = (L >> 1) & 15;
        int cb = ((L >> 5) << 3) + ((L & 1) << 2);
        union { _Float16 h[4]; unsigned long long u; } sv;
#pragma unroll
        for (int q = 0; q < 4; q++) sv.h[q] = hstage2[w][rrow][cb + q];
        unsigned long long* dp =
            (unsigned long long*)(hw + (((size_t)(group * 32 + hblk)) << 9) +
                                  ((size_t)w << 8) + ((size_t)L << 2));
        unsigned* fptr = &flags[((hblk << 1) + w) << 4];
        unsigned ep = (unsigned)(t + 1);
        // plain stores: write-through L1 -> dirty in XCD L2; no fabric crossing
        asm volatile("global_store_dwordx2 %0, %1, off" :: "v"(dp), "v"(sv.u) : "memory");
        asm volatile("s_waitcnt vmcnt(0)" ::: "memory");  // h committed to L2 before flag
        if (L == 0)
          asm volatile("global_store_dword %0, %1, off" :: "v"(fptr), "v"(ep) : "memory");
      }

      // ax prefetch for t+1 (AFTER producer drain — hides under the poll)
      {
        int tn = (t + 1 < T_) ? (t + 1) : t;
        const half8* xb = xff + ((size_t)tn * 8 + group) * (16 * 64);
#pragma unroll
        for (int kx = 0; kx < 4; kx++) ax[kx] = xb[(w * 4 + kx) * 64 + L];
      }

      if (t + 1 < T_) {
        const unsigned tgt = (unsigned)(t + 1);
        // poll: exactly the 16 h-producer flags of my K chunk, s_sleep(1) backoff
        const unsigned* fp16 = &flags[(w * 16 + (L & 15)) << 4];
        while (true) {
          unsigned v = tgt;
          if (L < 16) {
            unsigned vv;
            asm volatile("global_load_dword %0, %1, off sc0 nt\n\ts_waitcnt vmcnt(0)"
                         : "=v"(vv) : "v"(fp16) : "memory");
            v = vv;
          }
          if (__all((int)(v >= tgt))) break;
          __builtin_amdgcn_s_sleep(1);
        }
        // intra-WG: red consumed by both producer waves (LDS, nearly always ready)
        while (true) {
          unsigned v = tgt;
          if (L < 2)
            v = __hip_atomic_load(&red_ep[L], __ATOMIC_ACQUIRE, __HIP_MEMORY_SCOPE_WORKGROUP);
          if (__all((int)(v >= tgt))) break;
        }
        __builtin_amdgcn_sched_barrier(0);  // pin: next-step ah loads issue after poll
      }
    }
  } else {
    // ================== SLOW LOOP (exact R6 agent-scope protocol) ==================
    for (int t = 0; t < T_; t++) {
      const _Float16* hb = hbuf + (size_t)(t & 1) * (B_ * H_);
      _Float16* hw = hbuf + (size_t)((t + 1) & 1) * (B_ * H_);

      f32x4 ahf[8];
      const _Float16* hbp =
          hb + (((size_t)group * 32 + (size_t)(w * 8)) << 9) + ((size_t)L << 3);
#pragma unroll
      for (int k8 = 0; k8 < 8; k8++) {
        const unsigned long long* ap = (const unsigned long long*)(hbp + ((size_t)k8 << 9));
        union { unsigned long long u[2]; f32x4 f; } cv;
        cv.u[0] = __hip_atomic_load(ap, __ATOMIC_RELAXED, __HIP_MEMORY_SCOPE_AGENT);
        cv.u[1] = __hip_atomic_load(ap + 1, __ATOMIC_RELAXED, __HIP_MEMORY_SCOPE_AGENT);
        ahf[k8] = cv.f;
      }

      f32x4 acc[8] = {};
#pragma unroll
      for (int kx = 0; kx < 4; kx++)
#pragma unroll
        for (int nt = 0; nt < 8; nt++)
          acc[nt] = __builtin_amdgcn_mfma_f32_16x16x32_f16(ax[kx], wxr[nt][kx], acc[nt], 0, 0, 0);
#pragma unroll
      for (int k8 = 0; k8 < 8; k8++)
#pragma unroll
        for (int nt = 0; nt < 8; nt++)
          acc[nt] = __builtin_amdgcn_mfma_f32_16x16x32_f16(as_h8(ahf[k8]), bw[nt][k8], acc[nt], 0, 0, 0);
#pragma unroll
      for (int nt = 0; nt < 8; nt++) red[w][nt][L] = acc[nt];
      __syncthreads();

      if (w < 2) {
        f32x4 gv[4];
#pragma unroll
        for (int g = 0; g < 4; g++) {
          f32x4 s = red[0][g * 2 + w][L];
          s += red[1][g * 2 + w][L];
          s += red[2][g * 2 + w][L];
          s += red[3][g * 2 + w][L];
          gv[g] = s;
        }
        if (L == 0)
          __hip_atomic_store(&red_ep[w], (unsigned)(t + 1), __ATOMIC_RELEASE,
                             __HIP_MEMORY_SCOPE_WORKGROUP);
#pragma unroll
        for (int r = 0; r < 4; r++) {
          float gi = gv[0][r] + bgr[0];
          float gf = gv[1][r] + bgr[1];
          float go = gv[2][r] + bgr[2];
          float gc = gv[3][r] + bgr[3];
          float c = fsigm(gf) * cst[r] + fsigm(gi) * ftanh(gc);
          cst[r] = c;
          hstage2[w][(quad << 2) + r][lo] = (_Float16)(fsigm(go) * ftanh(c));
        }
        __builtin_amdgcn_wave_barrier();
        asm volatile("s_waitcnt lgkmcnt(0)" ::: "memory");
        int rrow = (L >> 1) & 15;
        int cb = ((L >> 5) << 3) + ((L & 1) << 2);
        union { _Float16 h[4]; unsigned long long u; } sv;
#pragma unroll
        for (int q = 0; q < 4; q++) sv.h[q] = hstage2[w][rrow][cb + q];
        unsigned long long* dp =
            (unsigned long long*)(hw + (((size_t)(group * 32 + hblk)) << 9) +
                                  ((size_t)w << 8) + ((size_t)L << 2));
        unsigned* fptr = &flags[((hblk << 1) + w) << 4];
        unsigned ep = (unsigned)(t + 1);
        __hip_atomic_store(dp, sv.u, __ATOMIC_RELAXED, __HIP_MEMORY_SCOPE_AGENT);
        asm volatile("s_waitcnt vmcnt(0)" ::: "memory");
        if (L == 0)
          __hip_atomic_store(fptr, ep, __ATOMIC_RELAXED, __HIP_MEMORY_SCOPE_AGENT);
      }

      {
        int tn = (t + 1 < T_) ? (t + 1) : t;
        const half8* xb = xff + ((size_t)tn * 8 + group) * (16 * 64);
#pragma unroll
        for (int kx = 0; kx < 4; kx++) ax[kx] = xb[(w * 4 + kx) * 64 + L];
      }

      if (t + 1 < T_) {
        const unsigned tgt = (unsigned)(t + 1);
        while (true) {
          unsigned v = tgt;
          if (L < 16)
            v = __hip_atomic_load(&flags[(w * 16 + L) << 4], __ATOMIC_RELAXED,
                                  __HIP_MEMORY_SCOPE_AGENT);
          if (__all((int)(v >= tgt))) break;
          __builtin_amdgcn_s_sleep(1);
        }
        while (true) {
          unsigned v = tgt;
          if (L < 2)
            v = __hip_atomic_load(&red_ep[L], __ATOMIC_ACQUIRE, __HIP_MEMORY_SCOPE_WORKGROUP);
          if (__all((int)(v >= tgt))) break;
        }
        __builtin_amdgcn_sched_barrier(0);
      }
    }
  }
}

// ---------------- final: softmax(h @ W_hq + b_q), h in frag layout ----------------
__global__ __launch_bounds__(64) void k_final(const char* __restrict__ ws,
                                              const float* __restrict__ Whq,
                                              const float* __restrict__ bq,
                                              float* __restrict__ out) {
  const int b = blockIdx.x;
  const int l = threadIdx.x;
  const _Float16* hf = (const _Float16*)(ws + HBUF_OFF);  // h_512 in buf 0 (T even)
  const int g = b >> 4, row = b & 15;
  float s[10];
#pragma unroll
  for (int o = 0; o < 10; o++) s[o] = 0.f;
  for (int k = l; k < H_; k += 64) {
    int kk = k >> 5, q = (k >> 3) & 3, j = k & 7;
    float hv = (float)hf[(((size_t)g * 32 + kk) * 64 + (row | (q << 4))) * 8 + j];
    const float* wr = Whq + (size_t)k * 10;
#pragma unroll
    for (int o = 0; o < 10; o++) s[o] += hv * wr[o];
  }
#pragma unroll
  for (int o = 0; o < 10; o++) {
#pragma unroll
    for (int d = 32; d > 0; d >>= 1) s[o] += __shfl_down(s[o], d);
  }
  if (l == 0) {
    float mx = -1e30f;
    for (int o = 0; o < 10; o++) { s[o] += bq[o]; mx = fmaxf(mx, s[o]); }
    float ssum = 0.f, ex[10];
    for (int o = 0; o < 10; o++) { ex[o] = __expf(s[o] - mx); ssum += ex[o]; }
    for (int o = 0; o < 10; o++) out[b * 10 + o] = ex[o] / ssum;
  }
}

extern "C" void kernel_launch(void* const* d_in, const int* in_sizes, int n_in,
                              void* d_out, int out_size, void* d_ws, size_t ws_size,
                              hipStream_t stream) {
  const int* ids   = (const int*)d_in[0];
  const float* emb = (const float*)d_in[1];
  const float* Wxi = (const float*)d_in[2];
  const float* Whi = (const float*)d_in[3];
  const float* bi  = (const float*)d_in[4];
  const float* Wxf = (const float*)d_in[5];
  const float* Whf = (const float*)d_in[6];
  const float* bfv = (const float*)d_in[7];
  const float* Wxo = (const float*)d_in[8];
  const float* Who = (const float*)d_in[9];
  const float* bo  = (const float*)d_in[10];
  const float* Wxc = (const float*)d_in[11];
  const float* Whc = (const float*)d_in[12];
  const float* bc  = (const float*)d_in[13];
  const float* Whq = (const float*)d_in[14];
  const float* bq  = (const float*)d_in[15];
  float* out = (float*)d_out;
  char* ws = (char*)d_ws;

  if (ws_size < WS_NEED) {
    k_diag<<<(out_size + 255) / 256, 256, 0, stream>>>(out, out_size, (unsigned)(ws_size >> 20));
    return;
  }

  k_prep<<<3217, 256, 0, stream>>>(Wxi, Wxf, Wxo, Wxc, Whi, Whf, Who, Whc, bi, bfv, bo, bc, ws);
  k_embed<<<512, 256, 0, stream>>>(ids, emb, ws);
  k_lstm<<<256, 256, 0, stream>>>(ws);
  k_final<<<128, 64, 0, stream>>>(ws, Whq, bq, out);
}

// Round 9
// 1771.400 us; speedup vs baseline: 1.1538x; 1.0794x over previous
//
#include <hip/hip_runtime.h>
#include <hip/hip_fp16.h>

#define V_ 50000
#define E_ 512
#define H_ 1024
#define B_ 128
#define T_ 512
#define NG 4096  // 4*H

typedef _Float16 half8 __attribute__((ext_vector_type(8)));
typedef float f32x4 __attribute__((ext_vector_type(4)));

// ---- workspace layout (bytes) ----
static constexpr size_t WX_OFF   = 0;                                        // 4 MiB: Wx f16 B-frags [ntg 256][kt 16][L 64] half8
static constexpr size_t WH_OFF   = (size_t)4 << 20;                          // 8 MiB: Wh f16 B-frags [hblk 32][nt 8][kt 32][L 64] half8
static constexpr size_t BG_OFF   = (size_t)12 << 20;                         // 16 KiB: bias concat f32 [4096]
static constexpr size_t HBUF_OFF = ((size_t)12 << 20) + ((size_t)64 << 10);  // 512 KiB: h dbuf [2][g 8][kk 32][L 64] half8 (A-frag layout)
static constexpr size_t BAR_OFF  = ((size_t)12 << 20) + ((size_t)640 << 10); // 81 KiB: flags[8][64] + probe[8][64] + votes[8][32] + xcd_ctr[8], u32, 64B-padded
static constexpr size_t XF_OFF   = (size_t)16 << 20;                         // 64 MiB: xf f16 frag layout [t][g 8][kk 16][L 64] half8
static constexpr size_t WS_NEED  = XF_OFF + (size_t)T_ * B_ * E_ * 2;        // 80 MiB

__device__ __forceinline__ float fsigm(float x) { return 1.f / (1.f + __expf(-x)); }
__device__ __forceinline__ float ftanh(float x) {
  float cx = fminf(fmaxf(x, -15.f), 15.f);
  float e = __expf(2.f * cx);
  return (e - 1.f) / (e + 1.f);
}
__device__ __forceinline__ half8 as_h8(f32x4 x) {
  union { f32x4 f; half8 h; } u; u.f = x; return u.h;
}

// ---------------- diag: ws too small — encode ws MiB in out[0] ----------------
__global__ void k_diag(float* __restrict__ out, int n, unsigned wsmb) {
  int i = blockIdx.x * 256 + threadIdx.x;
  if (i < n) out[i] = (i == 0) ? (float)wsmb : 0.1f;
}

// ---------------- prep: frag-layout weights, zero h/flags ----------------
__global__ __launch_bounds__(256) void k_prep(
    const float* __restrict__ Wxi, const float* __restrict__ Wxf,
    const float* __restrict__ Wxo, const float* __restrict__ Wxc,
    const float* __restrict__ Whi, const float* __restrict__ Whf,
    const float* __restrict__ Who, const float* __restrict__ Whc,
    const float* __restrict__ bi, const float* __restrict__ bfp,
    const float* __restrict__ bo, const float* __restrict__ bc,
    char* __restrict__ ws) {
  half8* wx = (half8*)(ws + WX_OFF);
  half8* wh = (half8*)(ws + WH_OFF);
  float* bg = (float*)(ws + BG_OFF);
  half8* hb = (half8*)(ws + HBUF_OFF);
  unsigned* bar = (unsigned*)(ws + BAR_OFF);
  const float* WxA[4] = {Wxi, Wxf, Wxo, Wxc};
  const float* WhA[4] = {Whi, Whf, Who, Whc};
  const float* bA[4]  = {bi, bfp, bo, bc};

  const int ZWX = 256 * 16 * 64;      // 262144 frags
  const int ZWH = 32 * 8 * 32 * 64;   // 524288 frags
  const int ZBG = NG;
  const int ZHB = 2 * B_ * H_ / 8;    // 32768 half8
  const int ZBAR = 8 * 64 * 16 + 8 * 64 * 16 + 8 * 32 * 16 + 8 * 16;  // flags+probe+votes+ctr
  const int total = ZWX + ZWH + ZBG + ZHB + ZBAR;

  for (int it = blockIdx.x * 256 + threadIdx.x; it < total; it += gridDim.x * 256) {
    int i = it;
    if (i < ZWX) {
      // B-frag elem j = Wx_gate[k = kt*32 + quad*8 + j][col]; ntg = g*64 + hblk*2 + ct
      int L = i & 63, kt = (i >> 6) & 15, ntg = i >> 10;
      int gate = ntg >> 6;
      int col = ((ntg & 63) << 4) + (L & 15);
      int k0 = (kt << 5) + ((L >> 4) << 3);
      const float* src = WxA[gate] + (size_t)k0 * H_ + col;
      half8 v;
#pragma unroll
      for (int j = 0; j < 8; j++) v[j] = (_Float16)src[(size_t)j * H_];
      wx[i] = v;
    } else if ((i -= ZWX) < ZWH) {
      // layout [hbk 32][nt 8][kt 32][L 64]; nt = g*2+ct; col = hbk*32 + ct*16 + (L&15)
      int L = i & 63, kt = (i >> 6) & 31, nt = (i >> 11) & 7, hbk = i >> 14;
      int ct = nt & 1, g = nt >> 1;
      int col = (hbk << 5) + (ct << 4) + (L & 15);
      int k0 = (kt << 5) + ((L >> 4) << 3);
      const float* src = WhA[g] + (size_t)k0 * H_ + col;
      half8 v;
#pragma unroll
      for (int j = 0; j < 8; j++) v[j] = (_Float16)src[(size_t)j * H_];
      wh[i] = v;
    } else if ((i -= ZWH) < ZBG) {
      bg[i] = bA[i >> 10][i & 1023];
    } else if ((i -= ZBG) < ZHB) {
      half8 z = {};
      hb[i] = z;
    } else {
      i -= ZHB;
      bar[i] = 0u;
    }
  }
}

// ---------------- embed: xf in A-frag layout ----------------
// x[b][k] -> g=b>>4,row=b&15, kk=k>>5,q=(k>>3)&3,j=k&7 : xf[(t*8+g)*16+kk][row|(q<<4)][j]
__global__ __launch_bounds__(256) void k_embed(const int* __restrict__ ids,
                                               const float* __restrict__ emb,
                                               char* __restrict__ ws) {
  half8* xf = (half8*)(ws + XF_OFF);
  const int t = blockIdx.x;
  for (int p = threadIdx.x; p < 128 * 64; p += 256) {
    int b = p >> 6, c8 = p & 63;  // c8: which aligned 8-elem chunk of E (kk=c8>>2, q=c8&3)
    int id = ids[b * T_ + t];
    const float* er = emb + (size_t)id * E_ + (c8 << 3);
    float4 f0 = *(const float4*)er;
    float4 f1 = *(const float4*)(er + 4);
    half8 v;
    v[0] = (_Float16)f0.x; v[1] = (_Float16)f0.y; v[2] = (_Float16)f0.z; v[3] = (_Float16)f0.w;
    v[4] = (_Float16)f1.x; v[5] = (_Float16)f1.y; v[6] = (_Float16)f1.z; v[7] = (_Float16)f1.w;
    int g = b >> 4, row = b & 15;
    xf[((size_t)(t * 8 + g) * 16 + (c8 >> 2)) * 64 + (row | ((c8 & 3) << 4))] = v;
  }
}

// ---------------- fused persistent recurrence + input projection ----------------
// R6 structure (XCD-local groups by construction + bounded sc0 probe + agent fallback).
// R9 = R6 loop with ONE change (R8 refuted Wx-under-ah-flight; reverted):
//   producer h-write is now a DIRECT frag-layout scattered store from gate registers
//   (4x global_store_short per lane; halfword idx = blk*512 + w*256 + (lo>>3)*128 +
//   quad*32 + r*8 + (lo&7), algebraically identical to the old LDS-transpose path) —
//   eliminating the hstage2 round trip (4 ds_write + wave_barrier + lgkmcnt + 4 ds_read)
//   from the producer tail. Stores spread under gate VALU; drain waits only them.
// Slow path: exact R6 agent-scope loop (proven).
__global__ __launch_bounds__(256, 1) void k_lstm(char* __restrict__ ws) {
  __shared__ f32x4 red[4][8][64];          // 32 KB
  __shared__ _Float16 hstage2[2][16][16];  // 1 KB: transpose tile (slow path only)
  __shared__ unsigned red_ep[2];           // intra-WG "red consumed" epochs
  __shared__ int wok[4];                   // per-wave probe results
  __shared__ unsigned sslot, sbal;         // runtime role slot / balanced flag
  const half8* whf = (const half8*)(ws + WH_OFF);
  const half8* wxg = (const half8*)(ws + WX_OFF);
  const float* bgp = (const float*)(ws + BG_OFF);
  _Float16* hbuf = (_Float16*)(ws + HBUF_OFF);
  const half8* xff = (const half8*)(ws + XF_OFF);
  unsigned* bar = (unsigned*)(ws + BAR_OFF);

  const int wg = blockIdx.x;
  const int tid = threadIdx.x;
  const int L = tid & 63, w = tid >> 6;
  const int lo = L & 15, quad = L >> 4;
  unsigned* ctrp = bar + 20480;  // 8 xcd counters, 64B apart

  // ---- runtime role claim: group = my XCD, hblk = slot within it ----
  unsigned myxid;
  asm volatile("s_getreg_b32 %0, hwreg(HW_REG_XCC_ID)" : "=s"(myxid));
  myxid &= 7u;
  if (tid == 0)
    sslot = __hip_atomic_fetch_add(&ctrp[myxid * 16], 1u, __ATOMIC_RELAXED,
                                   __HIP_MEMORY_SCOPE_AGENT);
  __syncthreads();
  const unsigned slot = __builtin_amdgcn_readfirstlane(sslot);
  if (tid == 0) {
    // wait until all 256 WGs registered (terminates: co-resident grid), then check balance
    unsigned cnt[8];
    while (true) {
      unsigned s = 0;
#pragma unroll
      for (int x = 0; x < 8; x++) {
        cnt[x] = __hip_atomic_load(&ctrp[x * 16], __ATOMIC_RELAXED, __HIP_MEMORY_SCOPE_AGENT);
        s += cnt[x];
      }
      if (s == 256u) break;
      __builtin_amdgcn_s_sleep(4);
    }
    unsigned ok = 1u;
#pragma unroll
    for (int x = 0; x < 8; x++) ok &= (cnt[x] == 32u) ? 1u : 0u;
    sbal = ok;
  }
  __syncthreads();
  const bool balanced = sbal != 0u;
  const int group = balanced ? (int)myxid : (wg & 7);   // batches [group*16, +16)
  const int hblk  = balanced ? (int)slot  : (wg >> 3);  // h-cols [hblk*32, +32) x 4 gates
  const int hbase = hblk << 5;
  unsigned* flags = bar + group * 1024;          // 4KB/group: 64 producer flags, 64B apart
  unsigned* probe = bar + 8192 + group * 1024;   // 4KB/group: 64 probe tokens, 64B apart
  unsigned* votes = bar + 16384 + group * 512;   // 2KB/group: 32 WG votes, 64B apart

  // probe token: plain store (write-through L1 -> dirty in MY XCD's L2)
  if (balanced && w < 2 && L == 0) {
    unsigned one = 1u;
    unsigned* pp = &probe[((hblk << 1) + w) << 4];
    asm volatile("global_store_dword %0, %1, off" :: "v"(pp), "v"(one) : "memory");
  }

  // B-frags (register/AGPR-resident): Wh [nt][k8] for K chunk [w*256,+256)
  half8 bw[8][8];
#pragma unroll
  for (int nt = 0; nt < 8; nt++)
#pragma unroll
    for (int k8 = 0; k8 < 8; k8++)
      bw[nt][k8] = whf[((size_t)(hblk * 8 + nt) * 32 + w * 8 + k8) * 64 + L];
  // Wx [nt][kx] for K chunk [w*128,+128); ntg = g*64 + hblk*2 + ct, nt = g*2+ct
  half8 wxr[8][4];
#pragma unroll
  for (int nt = 0; nt < 8; nt++)
#pragma unroll
    for (int kx = 0; kx < 4; kx++)
      wxr[nt][kx] =
          wxg[(size_t)(((nt >> 1) * 64 + (hblk << 1) + (nt & 1)) * 16 + w * 4 + kx) * 64 + L];

  // ---- bounded behavioral probe of the sc0-load/plain-store exchange ----
  bool fast = false;
  if (balanced) {
    int okw = 0;
    for (int it = 0; it < 1500 && !okw; ++it) {
      unsigned v = 1u;
      if (L < 16) {
        const unsigned* pp = &probe[(w * 16 + L) << 4];
        unsigned vv;
        asm volatile("global_load_dword %0, %1, off sc0 nt\n\ts_waitcnt vmcnt(0)"
                     : "=v"(vv) : "v"(pp) : "memory");
        v = vv;
      }
      okw = __all((int)(v != 0u));
      if (!okw) __builtin_amdgcn_s_sleep(2);
    }
    if (L == 0) wok[w] = okw;
    __syncthreads();
    const int allok = wok[0] & wok[1] & wok[2] & wok[3];
    if (tid == 0)
      __hip_atomic_store(&votes[hblk << 4], (unsigned)(allok ? 2 : 1),
                         __ATOMIC_RELAXED, __HIP_MEMORY_SCOPE_AGENT);
    unsigned fastu;
    while (true) {
      unsigned v = 2u;
      if (L < 32)
        v = __hip_atomic_load(&votes[L << 4], __ATOMIC_RELAXED, __HIP_MEMORY_SCOPE_AGENT);
      if (__all((int)(v != 0u))) { fastu = (unsigned)__all((int)(v == 2u)); break; }
      __builtin_amdgcn_s_sleep(8);
    }
    fast = fastu != 0;
  }

  float bgr[4] = {};
  f32x4 cst = {};
  if (w < 2) {  // update lanes: ct = w; (b = group*16 + quad*4 + r, col = hbase + w*16 + lo)
#pragma unroll
    for (int g = 0; g < 4; g++) bgr[g] = bgp[g * H_ + hbase + (w << 4) + lo];
  }
  if (tid < 2) red_ep[tid] = 0u;

  // preload ax (frag layout, plain cached loads) for t=0
  half8 ax[4];
  {
    const half8* xb = xff + (size_t)group * (16 * 64);
#pragma unroll
    for (int kx = 0; kx < 4; kx++) ax[kx] = xb[(w * 4 + kx) * 64 + L];
  }
  __syncthreads();

  if (fast) {
    // ================== FAST LOOP (R6 order + direct frag h-stores) ==================
    // direct-store halfword base for producer lane: blk*512 + w*256 + (lo>>3)*128 + quad*32 + (lo&7)
    for (int t = 0; t < T_; t++) {
      const _Float16* hb = hbuf + (size_t)(t & 1) * (B_ * H_);
      _Float16* hw = hbuf + (size_t)((t + 1) & 1) * (B_ * H_);

      // (1) issue 8 ah loads (sc0 nt: L1-bypass, XCD-L2-served), wait, then all MFMAs
      f32x4 ahf[8];
      const _Float16* hbp =
          hb + (((size_t)group * 32 + (size_t)(w * 8)) << 9) + ((size_t)L << 3);
      const _Float16* hbp2 = hbp + ((size_t)4 << 9);
      asm volatile("global_load_dwordx4 %0, %1, off sc0 nt"             : "=v"(ahf[0]) : "v"(hbp));
      asm volatile("global_load_dwordx4 %0, %1, off offset:1024 sc0 nt" : "=v"(ahf[1]) : "v"(hbp));
      asm volatile("global_load_dwordx4 %0, %1, off offset:2048 sc0 nt" : "=v"(ahf[2]) : "v"(hbp));
      asm volatile("global_load_dwordx4 %0, %1, off offset:3072 sc0 nt" : "=v"(ahf[3]) : "v"(hbp));
      asm volatile("global_load_dwordx4 %0, %1, off sc0 nt"             : "=v"(ahf[4]) : "v"(hbp2));
      asm volatile("global_load_dwordx4 %0, %1, off offset:1024 sc0 nt" : "=v"(ahf[5]) : "v"(hbp2));
      asm volatile("global_load_dwordx4 %0, %1, off offset:2048 sc0 nt" : "=v"(ahf[6]) : "v"(hbp2));
      asm volatile("global_load_dwordx4 %0, %1, off offset:3072 sc0 nt" : "=v"(ahf[7]) : "v"(hbp2));
      asm volatile("s_waitcnt vmcnt(0)" ::: "memory");
      __builtin_amdgcn_sched_barrier(0);  // rule #18: keep MFMAs below the waitcnt

      // (2) MFMA: Wx part then Wh part (R6 order — R8 refuted the alternative)
      f32x4 acc[8] = {};
#pragma unroll
      for (int kx = 0; kx < 4; kx++)
#pragma unroll
        for (int nt = 0; nt < 8; nt++)
          acc[nt] = __builtin_amdgcn_mfma_f32_16x16x32_f16(ax[kx], wxr[nt][kx], acc[nt], 0, 0, 0);
#pragma unroll
      for (int k8 = 0; k8 < 8; k8++)
#pragma unroll
        for (int nt = 0; nt < 8; nt++)
          acc[nt] = __builtin_amdgcn_mfma_f32_16x16x32_f16(as_h8(ahf[k8]), bw[nt][k8], acc[nt], 0, 0, 0);
#pragma unroll
      for (int nt = 0; nt < 8; nt++) red[w][nt][L] = acc[nt];
      __syncthreads();  // sync1: the ONLY per-step barrier (K-partials exchanged)

      if (w < 2) {
        // reduce partials
        f32x4 gv[4];
#pragma unroll
        for (int g = 0; g < 4; g++) {
          f32x4 s = red[0][g * 2 + w][L];
          s += red[1][g * 2 + w][L];
          s += red[2][g * 2 + w][L];
          s += red[3][g * 2 + w][L];
          gv[g] = s;
        }
        // signal red consumed (LDS, release)
        if (L == 0)
          __hip_atomic_store(&red_ep[w], (unsigned)(t + 1), __ATOMIC_RELEASE,
                             __HIP_MEMORY_SCOPE_WORKGROUP);
        // gate math + DIRECT frag-layout stores (2B each, issued as computed)
        _Float16* hwb = hw + (((size_t)(group * 32 + hblk)) << 9) + ((size_t)w << 8) +
                        ((size_t)(lo >> 3) << 7) + ((size_t)quad << 5) + (size_t)(lo & 7);
#pragma unroll
        for (int r = 0; r < 4; r++) {
          float gi = gv[0][r] + bgr[0];
          float gf = gv[1][r] + bgr[1];
          float go = gv[2][r] + bgr[2];
          float gc = gv[3][r] + bgr[3];
          float c = fsigm(gf) * cst[r] + fsigm(gi) * ftanh(gc);
          cst[r] = c;
          union { _Float16 h; unsigned short u; } hv;
          hv.h = (_Float16)(fsigm(go) * ftanh(c));
          unsigned hvu = hv.u;
          asm volatile("global_store_short %0, %1, off"
                       :: "v"(hwb + r * 8), "v"(hvu) : "memory");
        }
        asm volatile("s_waitcnt vmcnt(0)" ::: "memory");  // h committed to L2 before flag
        unsigned* fptr = &flags[((hblk << 1) + w) << 4];
        unsigned ep = (unsigned)(t + 1);
        if (L == 0)
          asm volatile("global_store_dword %0, %1, off" :: "v"(fptr), "v"(ep) : "memory");
      }

      // ax prefetch for t+1 (AFTER producer drain — hides under the poll)
      {
        int tn = (t + 1 < T_) ? (t + 1) : t;
        const half8* xb = xff + ((size_t)tn * 8 + group) * (16 * 64);
#pragma unroll
        for (int kx = 0; kx < 4; kx++) ax[kx] = xb[(w * 4 + kx) * 64 + L];
      }

      if (t + 1 < T_) {
        const unsigned tgt = (unsigned)(t + 1);
        // poll: exactly the 16 h-producer flags of my K chunk, s_sleep(1) backoff
        const unsigned* fp16 = &flags[(w * 16 + (L & 15)) << 4];
        while (true) {
          unsigned v = tgt;
          if (L < 16) {
            unsigned vv;
            asm volatile("global_load_dword %0, %1, off sc0 nt\n\ts_waitcnt vmcnt(0)"
                         : "=v"(vv) : "v"(fp16) : "memory");
            v = vv;
          }
          if (__all((int)(v >= tgt))) break;
          __builtin_amdgcn_s_sleep(1);
        }
        // intra-WG: red consumed by both producer waves (LDS, nearly always ready)
        while (true) {
          unsigned v = tgt;
          if (L < 2)
            v = __hip_atomic_load(&red_ep[L], __ATOMIC_ACQUIRE, __HIP_MEMORY_SCOPE_WORKGROUP);
          if (__all((int)(v >= tgt))) break;
        }
        __builtin_amdgcn_sched_barrier(0);  // pin: next-step ah loads issue after poll
      }
    }
  } else {
    // ================== SLOW LOOP (exact R6 agent-scope protocol) ==================
    for (int t = 0; t < T_; t++) {
      const _Float16* hb = hbuf + (size_t)(t & 1) * (B_ * H_);
      _Float16* hw = hbuf + (size_t)((t + 1) & 1) * (B_ * H_);

      f32x4 ahf[8];
      const _Float16* hbp =
          hb + (((size_t)group * 32 + (size_t)(w * 8)) << 9) + ((size_t)L << 3);
#pragma unroll
      for (int k8 = 0; k8 < 8; k8++) {
        const unsigned long long* ap = (const unsigned long long*)(hbp + ((size_t)k8 << 9));
        union { unsigned long long u[2]; f32x4 f; } cv;
        cv.u[0] = __hip_atomic_load(ap, __ATOMIC_RELAXED, __HIP_MEMORY_SCOPE_AGENT);
        cv.u[1] = __hip_atomic_load(ap + 1, __ATOMIC_RELAXED, __HIP_MEMORY_SCOPE_AGENT);
        ahf[k8] = cv.f;
      }

      f32x4 acc[8] = {};
#pragma unroll
      for (int kx = 0; kx < 4; kx++)
#pragma unroll
        for (int nt = 0; nt < 8; nt++)
          acc[nt] = __builtin_amdgcn_mfma_f32_16x16x32_f16(ax[kx], wxr[nt][kx], acc[nt], 0, 0, 0);
#pragma unroll
      for (int k8 = 0; k8 < 8; k8++)
#pragma unroll
        for (int nt = 0; nt < 8; nt++)
          acc[nt] = __builtin_amdgcn_mfma_f32_16x16x32_f16(as_h8(ahf[k8]), bw[nt][k8], acc[nt], 0, 0, 0);
#pragma unroll
      for (int nt = 0; nt < 8; nt++) red[w][nt][L] = acc[nt];
      __syncthreads();

      if (w < 2) {
        f32x4 gv[4];
#pragma unroll
        for (int g = 0; g < 4; g++) {
          f32x4 s = red[0][g * 2 + w][L];
          s += red[1][g * 2 + w][L];
          s += red[2][g * 2 + w][L];
          s += red[3][g * 2 + w][L];
          gv[g] = s;
        }
        if (L == 0)
          __hip_atomic_store(&red_ep[w], (unsigned)(t + 1), __ATOMIC_RELEASE,
                             __HIP_MEMORY_SCOPE_WORKGROUP);
#pragma unroll
        for (int r = 0; r < 4; r++) {
          float gi = gv[0][r] + bgr[0];
          float gf = gv[1][r] + bgr[1];
          float go = gv[2][r] + bgr[2];
          float gc = gv[3][r] + bgr[3];
          float c = fsigm(gf) * cst[r] + fsigm(gi) * ftanh(gc);
          cst[r] = c;
          hstage2[w][(quad << 2) + r][lo] = (_Float16)(fsigm(go) * ftanh(c));
        }
        __builtin_amdgcn_wave_barrier();
        asm volatile("s_waitcnt lgkmcnt(0)" ::: "memory");
        int rrow = (L >> 1) & 15;
        int cb = ((L >> 5) << 3) + ((L & 1) << 2);
        union { _Float16 h[4]; unsigned long long u; } sv;
#pragma unroll
        for (int q = 0; q < 4; q++) sv.h[q] = hstage2[w][rrow][cb + q];
        unsigned long long* dp =
            (unsigned long long*)(hw + (((size_t)(group * 32 + hblk)) << 9) +
                                  ((size_t)w << 8) + ((size_t)L << 2));
        unsigned* fptr = &flags[((hblk << 1) + w) << 4];
        unsigned ep = (unsigned)(t + 1);
        __hip_atomic_store(dp, sv.u, __ATOMIC_RELAXED, __HIP_MEMORY_SCOPE_AGENT);
        asm volatile("s_waitcnt vmcnt(0)" ::: "memory");
        if (L == 0)
          __hip_atomic_store(fptr, ep, __ATOMIC_RELAXED, __HIP_MEMORY_SCOPE_AGENT);
      }

      {
        int tn = (t + 1 < T_) ? (t + 1) : t;
        const half8* xb = xff + ((size_t)tn * 8 + group) * (16 * 64);
#pragma unroll
        for (int kx = 0; kx < 4; kx++) ax[kx] = xb[(w * 4 + kx) * 64 + L];
      }

      if (t + 1 < T_) {
        const unsigned tgt = (unsigned)(t + 1);
        while (true) {
          unsigned v = tgt;
          if (L < 16)
            v = __hip_atomic_load(&flags[(w * 16 + L) << 4], __ATOMIC_RELAXED,
                                  __HIP_MEMORY_SCOPE_AGENT);
          if (__all((int)(v >= tgt))) break;
          __builtin_amdgcn_s_sleep(1);
        }
        while (true) {
          unsigned v = tgt;
          if (L < 2)
            v = __hip_atomic_load(&red_ep[L], __ATOMIC_ACQUIRE, __HIP_MEMORY_SCOPE_WORKGROUP);
          if (__all((int)(v >= tgt))) break;
        }
        __builtin_amdgcn_sched_barrier(0);
      }
    }
  }
}

// ---------------- final: softmax(h @ W_hq + b_q), h in frag layout ----------------
__global__ __launch_bounds__(64) void k_final(const char* __restrict__ ws,
                                              const float* __restrict__ Whq,
                                              const float* __restrict__ bq,
                                              float* __restrict__ out) {
  const int b = blockIdx.x;
  const int l = threadIdx.x;
  const _Float16* hf = (const _Float16*)(ws + HBUF_OFF);  // h_512 in buf 0 (T even)
  const int g = b >> 4, row = b & 15;
  float s[10];
#pragma unroll
  for (int o = 0; o < 10; o++) s[o] = 0.f;
  for (int k = l; k < H_; k += 64) {
    int kk = k >> 5, q = (k >> 3) & 3, j = k & 7;
    float hv = (float)hf[(((size_t)g * 32 + kk) * 64 + (row | (q << 4))) * 8 + j];
    const float* wr = Whq + (size_t)k * 10;
#pragma unroll
    for (int o = 0; o < 10; o++) s[o] += hv * wr[o];
  }
#pragma unroll
  for (int o = 0; o < 10; o++) {
#pragma unroll
    for (int d = 32; d > 0; d >>= 1) s[o] += __shfl_down(s[o], d);
  }
  if (l == 0) {
    float mx = -1e30f;
    for (int o = 0; o < 10; o++) { s[o] += bq[o]; mx = fmaxf(mx, s[o]); }
    float ssum = 0.f, ex[10];
    for (int o = 0; o < 10; o++) { ex[o] = __expf(s[o] - mx); ssum += ex[o]; }
    for (int o = 0; o < 10; o++) out[b * 10 + o] = ex[o] / ssum;
  }
}

extern "C" void kernel_launch(void* const* d_in, const int* in_sizes, int n_in,
                              void* d_out, int out_size, void* d_ws, size_t ws_size,
                              hipStream_t stream) {
  const int* ids   = (const int*)d_in[0];
  const float* emb = (const float*)d_in[1];
  const float* Wxi = (const float*)d_in[2];
  const float* Whi = (const float*)d_in[3];
  const float* bi  = (const float*)d_in[4];
  const float* Wxf = (const float*)d_in[5];
  const float* Whf = (const float*)d_in[6];
  const float* bfv = (const float*)d_in[7];
  const float* Wxo = (const float*)d_in[8];
  const float* Who = (const float*)d_in[9];
  const float* bo  = (const float*)d_in[10];
  const float* Wxc = (const float*)d_in[11];
  const float* Whc = (const float*)d_in[12];
  const float* bc  = (const float*)d_in[13];
  const float* Whq = (const float*)d_in[14];
  const float* bq  = (const float*)d_in[15];
  float* out = (float*)d_out;
  char* ws = (char*)d_ws;

  if (ws_size < WS_NEED) {
    k_diag<<<(out_size + 255) / 256, 256, 0, stream>>>(out, out_size, (unsigned)(ws_size >> 20));
    return;
  }

  k_prep<<<3217, 256, 0, stream>>>(Wxi, Wxf, Wxo, Wxc, Whi, Whf, Who, Whc, bi, bfv, bo, bc, ws);
  k_embed<<<512, 256, 0, stream>>>(ids, emb, ws);
  k_lstm<<<256, 256, 0, stream>>>(ws);
  k_final<<<128, 64, 0, stream>>>(ws, Whq, bq, out);
}

// Round 10
// 1661.367 us; speedup vs baseline: 1.2302x; 1.0662x over previous
//
#include <hip/hip_runtime.h>
#include <hip/hip_fp16.h>

#define V_ 50000
#define E_ 512
#define H_ 1024
#define B_ 128
#define T_ 512
#define NG 4096  // 4*H

typedef _Float16 half8 __attribute__((ext_vector_type(8)));
typedef float f32x4 __attribute__((ext_vector_type(4)));

// ---- workspace layout (bytes) ----
static constexpr size_t WX_OFF   = 0;                                        // 4 MiB: Wx f16 B-frags [ntg 256][kt 16][L 64] half8
static constexpr size_t WH_OFF   = (size_t)4 << 20;                          // 8 MiB: Wh f16 B-frags [hblk 32][nt 8][kt 32][L 64] half8
static constexpr size_t BG_OFF   = (size_t)12 << 20;                         // 16 KiB: bias concat f32 [4096]
static constexpr size_t HBUF_OFF = ((size_t)12 << 20) + ((size_t)64 << 10);  // 512 KiB: h dbuf [2][g 8][kk 32][L 64] half8 (A-frag layout)
static constexpr size_t BAR_OFF  = ((size_t)12 << 20) + ((size_t)640 << 10); // 113 KiB: flags[8][128] + probe[8][64] + votes[8][32] + xcd_ctr[8], u32, 64B-padded
static constexpr size_t XF_OFF   = (size_t)16 << 20;                         // 64 MiB: xf f16 frag layout [t][g 8][kk 16][L 64] half8
static constexpr size_t WS_NEED  = XF_OFF + (size_t)T_ * B_ * E_ * 2;        // 80 MiB

__device__ __forceinline__ float fsigm(float x) { return 1.f / (1.f + __expf(-x)); }
__device__ __forceinline__ float ftanh(float x) {
  float cx = fminf(fmaxf(x, -15.f), 15.f);
  float e = __expf(2.f * cx);
  return (e - 1.f) / (e + 1.f);
}
__device__ __forceinline__ half8 as_h8(f32x4 x) {
  union { f32x4 f; half8 h; } u; u.f = x; return u.h;
}

// ---------------- diag: ws too small — encode ws MiB in out[0] ----------------
__global__ void k_diag(float* __restrict__ out, int n, unsigned wsmb) {
  int i = blockIdx.x * 256 + threadIdx.x;
  if (i < n) out[i] = (i == 0) ? (float)wsmb : 0.1f;
}

// ---------------- prep: frag-layout weights, zero h/flags ----------------
__global__ __launch_bounds__(256) void k_prep(
    const float* __restrict__ Wxi, const float* __restrict__ Wxf,
    const float* __restrict__ Wxo, const float* __restrict__ Wxc,
    const float* __restrict__ Whi, const float* __restrict__ Whf,
    const float* __restrict__ Who, const float* __restrict__ Whc,
    const float* __restrict__ bi, const float* __restrict__ bfp,
    const float* __restrict__ bo, const float* __restrict__ bc,
    char* __restrict__ ws) {
  half8* wx = (half8*)(ws + WX_OFF);
  half8* wh = (half8*)(ws + WH_OFF);
  float* bg = (float*)(ws + BG_OFF);
  half8* hb = (half8*)(ws + HBUF_OFF);
  unsigned* bar = (unsigned*)(ws + BAR_OFF);
  const float* WxA[4] = {Wxi, Wxf, Wxo, Wxc};
  const float* WhA[4] = {Whi, Whf, Who, Whc};
  const float* bA[4]  = {bi, bfp, bo, bc};

  const int ZWX = 256 * 16 * 64;      // 262144 frags
  const int ZWH = 32 * 8 * 32 * 64;   // 524288 frags
  const int ZBG = NG;
  const int ZHB = 2 * B_ * H_ / 8;    // 32768 half8
  const int ZBAR = 8 * 128 * 16 + 8 * 64 * 16 + 8 * 32 * 16 + 8 * 16;  // flags+probe+votes+ctr = 28800
  const int total = ZWX + ZWH + ZBG + ZHB + ZBAR;

  for (int it = blockIdx.x * 256 + threadIdx.x; it < total; it += gridDim.x * 256) {
    int i = it;
    if (i < ZWX) {
      // B-frag elem j = Wx_gate[k = kt*32 + quad*8 + j][col]; ntg = g*64 + hblk*2 + ct
      int L = i & 63, kt = (i >> 6) & 15, ntg = i >> 10;
      int gate = ntg >> 6;
      int col = ((ntg & 63) << 4) + (L & 15);
      int k0 = (kt << 5) + ((L >> 4) << 3);
      const float* src = WxA[gate] + (size_t)k0 * H_ + col;
      half8 v;
#pragma unroll
      for (int j = 0; j < 8; j++) v[j] = (_Float16)src[(size_t)j * H_];
      wx[i] = v;
    } else if ((i -= ZWX) < ZWH) {
      // layout [hbk 32][nt 8][kt 32][L 64]; nt = g*2+ct; col = hbk*32 + ct*16 + (L&15)
      int L = i & 63, kt = (i >> 6) & 31, nt = (i >> 11) & 7, hbk = i >> 14;
      int ct = nt & 1, g = nt >> 1;
      int col = (hbk << 5) + (ct << 4) + (L & 15);
      int k0 = (kt << 5) + ((L >> 4) << 3);
      const float* src = WhA[g] + (size_t)k0 * H_ + col;
      half8 v;
#pragma unroll
      for (int j = 0; j < 8; j++) v[j] = (_Float16)src[(size_t)j * H_];
      wh[i] = v;
    } else if ((i -= ZWH) < ZBG) {
      bg[i] = bA[i >> 10][i & 1023];
    } else if ((i -= ZBG) < ZHB) {
      half8 z = {};
      hb[i] = z;
    } else {
      i -= ZHB;
      bar[i] = 0u;
    }
  }
}

// ---------------- embed: xf in A-frag layout ----------------
// x[b][k] -> g=b>>4,row=b&15, kk=k>>5,q=(k>>3)&3,j=k&7 : xf[(t*8+g)*16+kk][row|(q<<4)][j]
__global__ __launch_bounds__(256) void k_embed(const int* __restrict__ ids,
                                               const float* __restrict__ emb,
                                               char* __restrict__ ws) {
  half8* xf = (half8*)(ws + XF_OFF);
  const int t = blockIdx.x;
  for (int p = threadIdx.x; p < 128 * 64; p += 256) {
    int b = p >> 6, c8 = p & 63;  // c8: which aligned 8-elem chunk of E (kk=c8>>2, q=c8&3)
    int id = ids[b * T_ + t];
    const float* er = emb + (size_t)id * E_ + (c8 << 3);
    float4 f0 = *(const float4*)er;
    float4 f1 = *(const float4*)(er + 4);
    half8 v;
    v[0] = (_Float16)f0.x; v[1] = (_Float16)f0.y; v[2] = (_Float16)f0.z; v[3] = (_Float16)f0.w;
    v[4] = (_Float16)f1.x; v[5] = (_Float16)f1.y; v[6] = (_Float16)f1.z; v[7] = (_Float16)f1.w;
    int g = b >> 4, row = b & 15;
    xf[((size_t)(t * 8 + g) * 16 + (c8 >> 2)) * 64 + (row | ((c8 & 3) << 4))] = v;
  }
}

// ---------------- fused persistent recurrence + input projection ----------------
// R6 structure (XCD-local groups by construction + bounded sc0 probe + agent fallback)
// + R9 direct frag-layout h-stores.
// R10: the update (reduce+gates+store+flag) is split across ALL 4 WAVES:
//   wave w handles (ct = w&1 column half, rh = w>>1 row half): 2 gate outputs/lane
//   instead of 4 (halves the serial transcendental chain), 2 stores, OWN flag
//   (4 flags/WG, 128/group, 64B-padded). Poll widens to 32 lanes (one instr).
//   WAR safety unchanged: union of 4 waves' poll sets = all 128 flags(t) =>
//   every WG finished step-t reads before any t+1 h-store; red overwrite gated
//   by red_ep[4] (each wave signals after its reduce-reads).
// Slow path: exact R6 agent-scope loop (proven).
__global__ __launch_bounds__(256, 1) void k_lstm(char* __restrict__ ws) {
  __shared__ f32x4 red[4][8][64];          // 32 KB
  __shared__ _Float16 hstage2[2][16][16];  // 1 KB: transpose tile (slow path only)
  __shared__ unsigned red_ep[4];           // intra-WG "red consumed" epochs (fast: 4)
  __shared__ int wok[4];                   // per-wave probe results
  __shared__ unsigned sslot, sbal;         // runtime role slot / balanced flag
  const half8* whf = (const half8*)(ws + WH_OFF);
  const half8* wxg = (const half8*)(ws + WX_OFF);
  const float* bgp = (const float*)(ws + BG_OFF);
  _Float16* hbuf = (_Float16*)(ws + HBUF_OFF);
  const half8* xff = (const half8*)(ws + XF_OFF);
  unsigned* bar = (unsigned*)(ws + BAR_OFF);

  const int wg = blockIdx.x;
  const int tid = threadIdx.x;
  const int L = tid & 63, w = tid >> 6;
  const int lo = L & 15, quad = L >> 4;
  unsigned* ctrp = bar + 28672;  // 8 xcd counters, 64B apart

  // ---- runtime role claim: group = my XCD, hblk = slot within it ----
  unsigned myxid;
  asm volatile("s_getreg_b32 %0, hwreg(HW_REG_XCC_ID)" : "=s"(myxid));
  myxid &= 7u;
  if (tid == 0)
    sslot = __hip_atomic_fetch_add(&ctrp[myxid * 16], 1u, __ATOMIC_RELAXED,
                                   __HIP_MEMORY_SCOPE_AGENT);
  __syncthreads();
  const unsigned slot = __builtin_amdgcn_readfirstlane(sslot);
  if (tid == 0) {
    // wait until all 256 WGs registered (terminates: co-resident grid), then check balance
    unsigned cnt[8];
    while (true) {
      unsigned s = 0;
#pragma unroll
      for (int x = 0; x < 8; x++) {
        cnt[x] = __hip_atomic_load(&ctrp[x * 16], __ATOMIC_RELAXED, __HIP_MEMORY_SCOPE_AGENT);
        s += cnt[x];
      }
      if (s == 256u) break;
      __builtin_amdgcn_s_sleep(4);
    }
    unsigned ok = 1u;
#pragma unroll
    for (int x = 0; x < 8; x++) ok &= (cnt[x] == 32u) ? 1u : 0u;
    sbal = ok;
  }
  __syncthreads();
  const bool balanced = sbal != 0u;
  const int group = balanced ? (int)myxid : (wg & 7);   // batches [group*16, +16)
  const int hblk  = balanced ? (int)slot  : (wg >> 3);  // h-cols [hblk*32, +32) x 4 gates
  const int hbase = hblk << 5;
  unsigned* flags = bar + group * 2048;          // 8KB/group: 128 producer flags, 64B apart
  unsigned* probe = bar + 16384 + group * 1024;  // 4KB/group: 64 probe tokens, 64B apart
  unsigned* votes = bar + 24576 + group * 512;   // 2KB/group: 32 WG votes, 64B apart

  // probe token: plain store (write-through L1 -> dirty in MY XCD's L2)
  if (balanced && w < 2 && L == 0) {
    unsigned one = 1u;
    unsigned* pp = &probe[((hblk << 1) + w) << 4];
    asm volatile("global_store_dword %0, %1, off" :: "v"(pp), "v"(one) : "memory");
  }

  // B-frags (register/AGPR-resident): Wh [nt][k8] for K chunk [w*256,+256)
  half8 bw[8][8];
#pragma unroll
  for (int nt = 0; nt < 8; nt++)
#pragma unroll
    for (int k8 = 0; k8 < 8; k8++)
      bw[nt][k8] = whf[((size_t)(hblk * 8 + nt) * 32 + w * 8 + k8) * 64 + L];
  // Wx [nt][kx] for K chunk [w*128,+128); ntg = g*64 + hblk*2 + ct, nt = g*2+ct
  half8 wxr[8][4];
#pragma unroll
  for (int nt = 0; nt < 8; nt++)
#pragma unroll
    for (int kx = 0; kx < 4; kx++)
      wxr[nt][kx] =
          wxg[(size_t)(((nt >> 1) * 64 + (hblk << 1) + (nt & 1)) * 16 + w * 4 + kx) * 64 + L];

  // ---- bounded behavioral probe of the sc0-load/plain-store exchange ----
  bool fast = false;
  if (balanced) {
    int okw = 0;
    for (int it = 0; it < 1500 && !okw; ++it) {
      unsigned v = 1u;
      if (L < 16) {
        const unsigned* pp = &probe[(w * 16 + L) << 4];
        unsigned vv;
        asm volatile("global_load_dword %0, %1, off sc0 nt\n\ts_waitcnt vmcnt(0)"
                     : "=v"(vv) : "v"(pp) : "memory");
        v = vv;
      }
      okw = __all((int)(v != 0u));
      if (!okw) __builtin_amdgcn_s_sleep(2);
    }
    if (L == 0) wok[w] = okw;
    __syncthreads();
    const int allok = wok[0] & wok[1] & wok[2] & wok[3];
    if (tid == 0)
      __hip_atomic_store(&votes[hblk << 4], (unsigned)(allok ? 2 : 1),
                         __ATOMIC_RELAXED, __HIP_MEMORY_SCOPE_AGENT);
    unsigned fastu;
    while (true) {
      unsigned v = 2u;
      if (L < 32)
        v = __hip_atomic_load(&votes[L << 4], __ATOMIC_RELAXED, __HIP_MEMORY_SCOPE_AGENT);
      if (__all((int)(v != 0u))) { fastu = (unsigned)__all((int)(v == 2u)); break; }
      __builtin_amdgcn_s_sleep(8);
    }
    fast = fastu != 0;
  }

  // bias for my column half (fast: all waves ct=w&1; slow: waves 0/1 use ct=w as before)
  const int ct = w & 1, rh = w >> 1;
  float bgr[4] = {};
#pragma unroll
  for (int g = 0; g < 4; g++) bgr[g] = bgp[g * H_ + hbase + (ct << 4) + lo];
  f32x4 cst = {};        // slow path: 4 rows (waves 0/1)
  float cst2[2] = {};    // fast path: 2 rows (all waves, rh half)
  if (tid < 4) red_ep[tid] = 0u;

  // preload ax (frag layout, plain cached loads) for t=0
  half8 ax[4];
  {
    const half8* xb = xff + (size_t)group * (16 * 64);
#pragma unroll
    for (int kx = 0; kx < 4; kx++) ax[kx] = xb[(w * 4 + kx) * 64 + L];
  }
  __syncthreads();

  if (fast) {
    // ============ FAST LOOP (R9 + 4-wave update split) ============
    for (int t = 0; t < T_; t++) {
      const _Float16* hb = hbuf + (size_t)(t & 1) * (B_ * H_);
      _Float16* hw = hbuf + (size_t)((t + 1) & 1) * (B_ * H_);

      // (1) issue 8 ah loads (sc0 nt: L1-bypass, XCD-L2-served), wait, then all MFMAs
      f32x4 ahf[8];
      const _Float16* hbp =
          hb + (((size_t)group * 32 + (size_t)(w * 8)) << 9) + ((size_t)L << 3);
      const _Float16* hbp2 = hbp + ((size_t)4 << 9);
      asm volatile("global_load_dwordx4 %0, %1, off sc0 nt"             : "=v"(ahf[0]) : "v"(hbp));
      asm volatile("global_load_dwordx4 %0, %1, off offset:1024 sc0 nt" : "=v"(ahf[1]) : "v"(hbp));
      asm volatile("global_load_dwordx4 %0, %1, off offset:2048 sc0 nt" : "=v"(ahf[2]) : "v"(hbp));
      asm volatile("global_load_dwordx4 %0, %1, off offset:3072 sc0 nt" : "=v"(ahf[3]) : "v"(hbp));
      asm volatile("global_load_dwordx4 %0, %1, off sc0 nt"             : "=v"(ahf[4]) : "v"(hbp2));
      asm volatile("global_load_dwordx4 %0, %1, off offset:1024 sc0 nt" : "=v"(ahf[5]) : "v"(hbp2));
      asm volatile("global_load_dwordx4 %0, %1, off offset:2048 sc0 nt" : "=v"(ahf[6]) : "v"(hbp2));
      asm volatile("global_load_dwordx4 %0, %1, off offset:3072 sc0 nt" : "=v"(ahf[7]) : "v"(hbp2));
      asm volatile("s_waitcnt vmcnt(0)" ::: "memory");
      __builtin_amdgcn_sched_barrier(0);  // rule #18: keep MFMAs below the waitcnt

      // (2) MFMA: Wx part then Wh part
      f32x4 acc[8] = {};
#pragma unroll
      for (int kx = 0; kx < 4; kx++)
#pragma unroll
        for (int nt = 0; nt < 8; nt++)
          acc[nt] = __builtin_amdgcn_mfma_f32_16x16x32_f16(ax[kx], wxr[nt][kx], acc[nt], 0, 0, 0);
#pragma unroll
      for (int k8 = 0; k8 < 8; k8++)
#pragma unroll
        for (int nt = 0; nt < 8; nt++)
          acc[nt] = __builtin_amdgcn_mfma_f32_16x16x32_f16(as_h8(ahf[k8]), bw[nt][k8], acc[nt], 0, 0, 0);
#pragma unroll
      for (int nt = 0; nt < 8; nt++) red[w][nt][L] = acc[nt];
      __syncthreads();  // sync1: the ONLY per-step barrier (K-partials exchanged)

      // (3) 4-wave update: wave w = (ct, rh); 2 gate rows/lane
      {
        // reduce partials (proven conflict-free b128 pattern; use my 2 components)
        float ga[4], gb[4];
#pragma unroll
        for (int g = 0; g < 4; g++) {
          f32x4 s = red[0][g * 2 + ct][L];
          s += red[1][g * 2 + ct][L];
          s += red[2][g * 2 + ct][L];
          s += red[3][g * 2 + ct][L];
          ga[g] = rh ? s[2] : s[0];
          gb[g] = rh ? s[3] : s[1];
        }
        // signal red consumed (LDS, release)
        if (L == 0)
          __hip_atomic_store(&red_ep[w], (unsigned)(t + 1), __ATOMIC_RELEASE,
                             __HIP_MEMORY_SCOPE_WORKGROUP);
        // gate math + direct frag-layout stores (2B each)
        _Float16* hwb = hw + (((size_t)(group * 32 + hblk)) << 9) + ((size_t)ct << 8) +
                        ((size_t)(lo >> 3) << 7) + ((size_t)quad << 5) + ((size_t)rh << 4) +
                        (size_t)(lo & 7);
#pragma unroll
        for (int rr = 0; rr < 2; rr++) {
          float gi = (rr ? gb[0] : ga[0]) + bgr[0];
          float gf = (rr ? gb[1] : ga[1]) + bgr[1];
          float go = (rr ? gb[2] : ga[2]) + bgr[2];
          float gc = (rr ? gb[3] : ga[3]) + bgr[3];
          float c = fsigm(gf) * cst2[rr] + fsigm(gi) * ftanh(gc);
          cst2[rr] = c;
          union { _Float16 h; unsigned short u; } hv;
          hv.h = (_Float16)(fsigm(go) * ftanh(c));
          unsigned hvu = hv.u;
          asm volatile("global_store_short %0, %1, off"
                       :: "v"(hwb + rr * 8), "v"(hvu) : "memory");
        }
        asm volatile("s_waitcnt vmcnt(0)" ::: "memory");  // h committed to L2 before flag
        unsigned* fptr = &flags[((hblk << 2) + w) << 4];
        unsigned ep = (unsigned)(t + 1);
        if (L == 0)
          asm volatile("global_store_dword %0, %1, off" :: "v"(fptr), "v"(ep) : "memory");
      }

      // ax prefetch for t+1 (AFTER producer drain — hides under the poll)
      {
        int tn = (t + 1 < T_) ? (t + 1) : t;
        const half8* xb = xff + ((size_t)tn * 8 + group) * (16 * 64);
#pragma unroll
        for (int kx = 0; kx < 4; kx++) ax[kx] = xb[(w * 4 + kx) * 64 + L];
      }

      if (t + 1 < T_) {
        const unsigned tgt = (unsigned)(t + 1);
        // poll: the 32 producer flags (8 WGs x 4 waves) of my K chunk, s_sleep(1)
        const unsigned* fp32 = &flags[(w * 32 + (L & 31)) << 4];
        while (true) {
          unsigned v = tgt;
          if (L < 32) {
            unsigned vv;
            asm volatile("global_load_dword %0, %1, off sc0 nt\n\ts_waitcnt vmcnt(0)"
                         : "=v"(vv) : "v"(fp32) : "memory");
            v = vv;
          }
          if (__all((int)(v >= tgt))) break;
          __builtin_amdgcn_s_sleep(1);
        }
        // intra-WG: red consumed by all 4 waves (LDS, nearly always ready)
        while (true) {
          unsigned v = tgt;
          if (L < 4)
            v = __hip_atomic_load(&red_ep[L], __ATOMIC_ACQUIRE, __HIP_MEMORY_SCOPE_WORKGROUP);
          if (__all((int)(v >= tgt))) break;
        }
        __builtin_amdgcn_sched_barrier(0);  // pin: next-step ah loads issue after poll
      }
    }
  } else {
    // ================== SLOW LOOP (exact R6 agent-scope protocol) ==================
    for (int t = 0; t < T_; t++) {
      const _Float16* hb = hbuf + (size_t)(t & 1) * (B_ * H_);
      _Float16* hw = hbuf + (size_t)((t + 1) & 1) * (B_ * H_);

      f32x4 ahf[8];
      const _Float16* hbp =
          hb + (((size_t)group * 32 + (size_t)(w * 8)) << 9) + ((size_t)L << 3);
#pragma unroll
      for (int k8 = 0; k8 < 8; k8++) {
        const unsigned long long* ap = (const unsigned long long*)(hbp + ((size_t)k8 << 9));
        union { unsigned long long u[2]; f32x4 f; } cv;
        cv.u[0] = __hip_atomic_load(ap, __ATOMIC_RELAXED, __HIP_MEMORY_SCOPE_AGENT);
        cv.u[1] = __hip_atomic_load(ap + 1, __ATOMIC_RELAXED, __HIP_MEMORY_SCOPE_AGENT);
        ahf[k8] = cv.f;
      }

      f32x4 acc[8] = {};
#pragma unroll
      for (int kx = 0; kx < 4; kx++)
#pragma unroll
        for (int nt = 0; nt < 8; nt++)
          acc[nt] = __builtin_amdgcn_mfma_f32_16x16x32_f16(ax[kx], wxr[nt][kx], acc[nt], 0, 0, 0);
#pragma unroll
      for (int k8 = 0; k8 < 8; k8++)
#pragma unroll
        for (int nt = 0; nt < 8; nt++)
          acc[nt] = __builtin_amdgcn_mfma_f32_16x16x32_f16(as_h8(ahf[k8]), bw[nt][k8], acc[nt], 0, 0, 0);
#pragma unroll
      for (int nt = 0; nt < 8; nt++) red[w][nt][L] = acc[nt];
      __syncthreads();

      if (w < 2) {
        f32x4 gv[4];
#pragma unroll
        for (int g = 0; g < 4; g++) {
          f32x4 s = red[0][g * 2 + w][L];
          s += red[1][g * 2 + w][L];
          s += red[2][g * 2 + w][L];
          s += red[3][g * 2 + w][L];
          gv[g] = s;
        }
        if (L == 0)
          __hip_atomic_store(&red_ep[w], (unsigned)(t + 1), __ATOMIC_RELEASE,
                             __HIP_MEMORY_SCOPE_WORKGROUP);
#pragma unroll
        for (int r = 0; r < 4; r++) {
          float gi = gv[0][r] + bgr[0];
          float gf = gv[1][r] + bgr[1];
          float go = gv[2][r] + bgr[2];
          float gc = gv[3][r] + bgr[3];
          float c = fsigm(gf) * cst[r] + fsigm(gi) * ftanh(gc);
          cst[r] = c;
          hstage2[w][(quad << 2) + r][lo] = (_Float16)(fsigm(go) * ftanh(c));
        }
        __builtin_amdgcn_wave_barrier();
        asm volatile("s_waitcnt lgkmcnt(0)" ::: "memory");
        int rrow = (L >> 1) & 15;
        int cb = ((L >> 5) << 3) + ((L & 1) << 2);
        union { _Float16 h[4]; unsigned long long u; } sv;
#pragma unroll
        for (int q = 0; q < 4; q++) sv.h[q] = hstage2[w][rrow][cb + q];
        unsigned long long* dp =
            (unsigned long long*)(hw + (((size_t)(group * 32 + hblk)) << 9) +
                                  ((size_t)w << 8) + ((size_t)L << 2));
        unsigned* fptr = &flags[((hblk << 1) + w) << 4];
        unsigned ep = (unsigned)(t + 1);
        __hip_atomic_store(dp, sv.u, __ATOMIC_RELAXED, __HIP_MEMORY_SCOPE_AGENT);
        asm volatile("s_waitcnt vmcnt(0)" ::: "memory");
        if (L == 0)
          __hip_atomic_store(fptr, ep, __ATOMIC_RELAXED, __HIP_MEMORY_SCOPE_AGENT);
      }

      {
        int tn = (t + 1 < T_) ? (t + 1) : t;
        const half8* xb = xff + ((size_t)tn * 8 + group) * (16 * 64);
#pragma unroll
        for (int kx = 0; kx < 4; kx++) ax[kx] = xb[(w * 4 + kx) * 64 + L];
      }

      if (t + 1 < T_) {
        const unsigned tgt = (unsigned)(t + 1);
        while (true) {
          unsigned v = tgt;
          if (L < 16)
            v = __hip_atomic_load(&flags[(w * 16 + L) << 4], __ATOMIC_RELAXED,
                                  __HIP_MEMORY_SCOPE_AGENT);
          if (__all((int)(v >= tgt))) break;
          __builtin_amdgcn_s_sleep(1);
        }
        while (true) {
          unsigned v = tgt;
          if (L < 2)
            v = __hip_atomic_load(&red_ep[L], __ATOMIC_ACQUIRE, __HIP_MEMORY_SCOPE_WORKGROUP);
          if (__all((int)(v >= tgt))) break;
        }
        __builtin_amdgcn_sched_barrier(0);
      }
    }
  }
}

// ---------------- final: softmax(h @ W_hq + b_q), h in frag layout ----------------
__global__ __launch_bounds__(64) void k_final(const char* __restrict__ ws,
                                              const float* __restrict__ Whq,
                                              const float* __restrict__ bq,
                                              float* __restrict__ out) {
  const int b = blockIdx.x;
  const int l = threadIdx.x;
  const _Float16* hf = (const _Float16*)(ws + HBUF_OFF);  // h_512 in buf 0 (T even)
  const int g = b >> 4, row = b & 15;
  float s[10];
#pragma unroll
  for (int o = 0; o < 10; o++) s[o] = 0.f;
  for (int k = l; k < H_; k += 64) {
    int kk = k >> 5, q = (k >> 3) & 3, j = k & 7;
    float hv = (float)hf[(((size_t)g * 32 + kk) * 64 + (row | (q << 4))) * 8 + j];
    const float* wr = Whq + (size_t)k * 10;
#pragma unroll
    for (int o = 0; o < 10; o++) s[o] += hv * wr[o];
  }
#pragma unroll
  for (int o = 0; o < 10; o++) {
#pragma unroll
    for (int d = 32; d > 0; d >>= 1) s[o] += __shfl_down(s[o], d);
  }
  if (l == 0) {
    float mx = -1e30f;
    for (int o = 0; o < 10; o++) { s[o] += bq[o]; mx = fmaxf(mx, s[o]); }
    float ssum = 0.f, ex[10];
    for (int o = 0; o < 10; o++) { ex[o] = __expf(s[o] - mx); ssum += ex[o]; }
    for (int o = 0; o < 10; o++) out[b * 10 + o] = ex[o] / ssum;
  }
}

extern "C" void kernel_launch(void* const* d_in, const int* in_sizes, int n_in,
                              void* d_out, int out_size, void* d_ws, size_t ws_size,
                              hipStream_t stream) {
  const int* ids   = (const int*)d_in[0];
  const float* emb = (const float*)d_in[1];
  const float* Wxi = (const float*)d_in[2];
  const float* Whi = (const float*)d_in[3];
  const float* bi  = (const float*)d_in[4];
  const float* Wxf = (const float*)d_in[5];
  const float* Whf = (const float*)d_in[6];
  const float* bfv = (const float*)d_in[7];
  const float* Wxo = (const float*)d_in[8];
  const float* Who = (const float*)d_in[9];
  const float* bo  = (const float*)d_in[10];
  const float* Wxc = (const float*)d_in[11];
  const float* Whc = (const float*)d_in[12];
  const float* bc  = (const float*)d_in[13];
  const float* Whq = (const float*)d_in[14];
  const float* bq  = (const float*)d_in[15];
  float* out = (float*)d_out;
  char* ws = (char*)d_ws;

  if (ws_size < WS_NEED) {
    k_diag<<<(out_size + 255) / 256, 256, 0, stream>>>(out, out_size, (unsigned)(ws_size >> 20));
    return;
  }

  k_prep<<<3217, 256, 0, stream>>>(Wxi, Wxf, Wxo, Wxc, Whi, Whf, Who, Whc, bi, bfv, bo, bc, ws);
  k_embed<<<512, 256, 0, stream>>>(ids, emb, ws);
  k_lstm<<<256, 256, 0, stream>>>(ws);
  k_final<<<128, 64, 0, stream>>>(ws, Whq, bq, out);
}